// Round 2
// baseline (442.570 us; speedup 1.0000x reference)
//
#include <hip/hip_runtime.h>
#include <hip/hip_bf16.h>

typedef __hip_bfloat16 bf16;
using f32x4v = __attribute__((ext_vector_type(4))) float;
using bf16x8 = __attribute__((ext_vector_type(8))) short;

#define N_NODES 25000
#define N_PAD   25008
#define N_EDGES 400000
#define N_GR    100
#define EC 4

__device__ __forceinline__ bf16 tob(float v) { return __float2bfloat16(v); }
__device__ __forceinline__ float tanh_fast(float x) {
  float cx = fminf(fmaxf(x, -10.f), 10.f);
  float e = __expf(2.f * cx);
  return (e - 1.f) / (e + 1.f);
}

// ---------------- CSR build ----------------
__global__ __launch_bounds__(256) void hist_kernel(const int* __restrict__ dst, int* __restrict__ deg, int E) {
  int e = blockIdx.x * blockDim.x + threadIdx.x;
  if (e < E) atomicAdd(&deg[dst[e]], 1);
}

__global__ __launch_bounds__(1024) void scan_kernel(const int* __restrict__ deg, int* __restrict__ offs,
                                                    int* __restrict__ cur, int n) {
  __shared__ int wsum[16];
  __shared__ int wpre[16];
  int t = threadIdx.x, lane = t & 63, w = t >> 6;
  int carry = 0;
  for (int base = 0; base < n; base += 1024) {
    int v = (base + t < n) ? deg[base + t] : 0;
    int x = v;
    #pragma unroll
    for (int s = 1; s < 64; s <<= 1) { int y = __shfl_up(x, s); if (lane >= s) x += y; }
    if (lane == 63) wsum[w] = x;
    __syncthreads();
    if (w == 0 && lane < 16) {
      int ws_ = wsum[lane];
      int xs = ws_;
      #pragma unroll
      for (int s = 1; s < 16; s <<= 1) { int y = __shfl_up(xs, s); if (lane >= s) xs += y; }
      wpre[lane] = xs - ws_;
    }
    __syncthreads();
    int excl = carry + wpre[w] + x - v;
    if (base + t < n) { offs[base + t] = excl; cur[base + t] = excl; }
    carry += wpre[15] + wsum[15];
    __syncthreads();
  }
  if (t == 0) offs[n] = carry;
}

__global__ __launch_bounds__(256) void fill_kernel(const int* __restrict__ dst, int* __restrict__ cur,
                                                   int* __restrict__ elist, int E) {
  int e = blockIdx.x * blockDim.x + threadIdx.x;
  if (e < E) { int p = atomicAdd(&cur[dst[e]], 1); elist[p] = e; }
}

// ---------------- weight prep ----------------
// wE per layer (1352 f32): [e1t 22x12][e2t 22x12][e3t 22x12][e4L 22x12][e4G 22x12][attv 32]
// Wt per layer (32x352 bf16): Wt[o][d*11+kk] = conv_w[kk][d][o]  (o>=30 zero)
__global__ __launch_bounds__(256) void prep_kernel(const float* __restrict__ e1, const float* __restrict__ e2,
                                                   const float* __restrict__ e3, const float* __restrict__ e4,
                                                   const float* __restrict__ attv, const float* __restrict__ convw,
                                                   float* __restrict__ wE, bf16* __restrict__ Wt) {
  int i = blockIdx.x * blockDim.x + threadIdx.x;
  if (i < 2 * 1352) {
    int l = i / 1352, r = i % 1352;
    float v = 0.f;
    if (r < 264)       { int q = r;        int j = q / 12, k = q % 12; if (k < 11) v = e1[l*242 + k*22 + j]; }
    else if (r < 528)  { int q = r - 264;  int j = q / 12, k = q % 12; if (k < 11) v = e2[l*242 + k*22 + j]; }
    else if (r < 792)  { int q = r - 528;  int j = q / 12, k = q % 12; if (k < 11) v = e3[l*242 + k*22 + j]; }
    else if (r < 1056) { int q = r - 792;  int j = q / 12, k = q % 12; if (k < 11) v = e4[l*484 + j*11 + k]; }
    else if (r < 1320) { int q = r - 1056; int j = q / 12, k = q % 12; if (k < 11) v = e4[l*484 + (22 + j)*11 + k]; }
    else               { int d = r - 1320; v = attv[l*32 + d]; }
    wE[i] = v;
  }
  int t = i - 2 * 1352;
  if (t >= 0 && t < 2 * 32 * 352) {
    int l = t / (32 * 352), q = t % (32 * 352);
    int o = q / 352, dk = q % 352;
    int d = dk / 11, kk = dk % 11;
    float v = 0.f;
    if (o < 30) v = convw[l*10560 + (kk*32 + d)*30 + o];
    Wt[t] = tob(v);
  }
}

// ---------------- embedding / h_proj ----------------
__global__ __launch_bounds__(256) void emb_kernel(const float* __restrict__ x, const float* __restrict__ w,
                                                  const float* __restrict__ b, float* __restrict__ h, int N) {
  __shared__ float sw[16 * 32];
  __shared__ float sb[32];
  for (int i = threadIdx.x; i < 16 * 32; i += blockDim.x) sw[i] = w[i];
  if (threadIdx.x < 32) sb[threadIdx.x] = b[threadIdx.x];
  __syncthreads();
  int i = blockIdx.x * blockDim.x + threadIdx.x;
  if (i >= N * 32) return;
  int n = i >> 5, d = i & 31;
  float acc = sb[d];
  #pragma unroll
  for (int k = 0; k < 16; k++) acc += x[n*16 + k] * sw[k*32 + d];
  h[i] = acc;
}

__global__ __launch_bounds__(256) void hproj_kernel(const float* __restrict__ h, const float* __restrict__ w,
                                                    float* __restrict__ hp, int N) {
  __shared__ float sw[32 * 32];
  for (int i = threadIdx.x; i < 32 * 32; i += blockDim.x) sw[i] = w[i];
  __syncthreads();
  int i = blockIdx.x * blockDim.x + threadIdx.x;
  if (i >= N * 32) return;
  int n = i >> 5, d = i & 31;
  const float* hr = h + (size_t)n * 32;
  float acc = 0.f;
  #pragma unroll
  for (int k = 0; k < 32; k++) acc += hr[k] * sw[k*32 + d];
  hp[i] = acc;
}

// ---------------- edge MLP + raw attention ----------------
__device__ __forceinline__ void loadw12(const float4* base, int idx3, float* w) {
  float4 a = base[idx3], b = base[idx3 + 1], c = base[idx3 + 2];
  w[0]=a.x; w[1]=a.y; w[2]=a.z; w[3]=a.w;
  w[4]=b.x; w[5]=b.y; w[6]=b.z; w[7]=b.w;
  w[8]=c.x; w[9]=c.y; w[10]=c.z; w[11]=c.w;
}

__global__ __launch_bounds__(256) void edge_kernel(const float* __restrict__ eattr,
                                                   const int* __restrict__ srcA, const float* __restrict__ hp,
                                                   const float* __restrict__ wEl,
                                                   float* __restrict__ ea_out, float* __restrict__ raw_out, int E) {
  const float4* w4 = (const float4*)wEl;
  int e0 = blockIdx.x * (blockDim.x * EC) + threadIdx.x;
  int e[EC]; bool live[EC];
  float a[EC][11], acc[EC][11];
  #pragma unroll
  for (int c = 0; c < EC; c++) {
    e[c] = e0 + c * blockDim.x;
    live[c] = e[c] < E;
    #pragma unroll
    for (int k = 0; k < 11; k++) {
      a[c][k] = live[c] ? eattr[(size_t)e[c]*11 + k] : 0.f;
      acc[c][k] = 0.f;
    }
  }
  for (int j = 0; j < 22; j++) {
    float w[12], l1[EC], l2[EC], gg[EC];
    loadw12(w4, j*3, w);
    #pragma unroll
    for (int c = 0; c < EC; c++) { float s = 0.f;
      #pragma unroll
      for (int k = 0; k < 11; k++) s += a[c][k] * w[k];
      l1[c] = s; }
    loadw12(w4, 66 + j*3, w);
    #pragma unroll
    for (int c = 0; c < EC; c++) { float s = 0.f;
      #pragma unroll
      for (int k = 0; k < 11; k++) s += a[c][k] * w[k];
      l2[c] = s; }
    loadw12(w4, 132 + j*3, w);
    #pragma unroll
    for (int c = 0; c < EC; c++) { float s = 0.f;
      #pragma unroll
      for (int k = 0; k < 11; k++) s += a[c][k] * w[k];
      gg[c] = tanh_fast(l2[c]) * tanh_fast(s);
      l1[c] = fmaxf(l1[c], 0.f); }
    float wl[12], wg[12];
    loadw12(w4, 198 + j*3, wl);
    loadw12(w4, 264 + j*3, wg);
    #pragma unroll
    for (int c = 0; c < EC; c++) {
      #pragma unroll
      for (int k = 0; k < 11; k++) acc[c][k] += l1[c]*wl[k] + gg[c]*wg[k];
    }
  }
  const float* av = wEl + 1320;
  #pragma unroll
  for (int c = 0; c < EC; c++) {
    if (!live[c]) continue;
    float mean = 0.f;
    #pragma unroll
    for (int k = 0; k < 11; k++) { acc[c][k] = fmaxf(acc[c][k], 0.f); mean += acc[c][k]; }
    mean *= (1.f / 11.f);
    float4* er = (float4*)(ea_out + (size_t)e[c] * 12);
    er[0] = make_float4(acc[c][0], acc[c][1], acc[c][2], acc[c][3]);
    er[1] = make_float4(acc[c][4], acc[c][5], acc[c][6], acc[c][7]);
    er[2] = make_float4(acc[c][8], acc[c][9], acc[c][10], 0.f);
    int s = srcA[e[c]];
    const float4* hp4 = (const float4*)(hp + (size_t)s * 32);
    float dot = 0.f;
    #pragma unroll
    for (int q = 0; q < 8; q++) {
      float4 hv = hp4[q];
      dot += hv.x*av[q*4+0] + hv.y*av[q*4+1] + hv.z*av[q*4+2] + hv.w*av[q*4+3];
    }
    raw_out[e[c]] = mean * dot;
  }
}

// ---------------- per-node aggregation with online segment softmax ----------------
__global__ __launch_bounds__(256) void node_kernel(const int* __restrict__ offs, const int* __restrict__ elist,
                                                   const int* __restrict__ srcA,
                                                   const float4* __restrict__ eav, const float* __restrict__ raw,
                                                   const float* __restrict__ hp,
                                                   bf16* __restrict__ Abuf, float* __restrict__ atts, int N) {
  int wid = threadIdx.x >> 6, lane = threadIdx.x & 63;
  int half = lane >> 5, d = lane & 31;
  int n = blockIdx.x * 4 + wid;
  if (n >= N_PAD) return;
  bool valid = (n < N);
  int beg = 0, deg = 0;
  if (valid) { beg = offs[n]; deg = offs[n + 1] - beg; }

  float agg[11], watt[11];
  #pragma unroll
  for (int k = 0; k < 11; k++) { agg[k] = 0.f; watt[k] = 0.f; }
  float m = -1e30f, denom = 0.f;

  for (int j = half; j < deg; j += 2) {
    int eid = elist[beg + j];
    int s = srcA[eid];
    float xs = hp[(size_t)s * 32 + d];
    float r = raw[eid];
    float4 q0 = eav[(size_t)eid * 3 + 0];
    float4 q1 = eav[(size_t)eid * 3 + 1];
    float4 q2 = eav[(size_t)eid * 3 + 2];
    float ev[12];
    *(float4*)&ev[0] = q0; *(float4*)&ev[4] = q1; *(float4*)&ev[8] = q2;
    if (r > m) {
      float sc = __expf(m - r);
      denom *= sc;
      #pragma unroll
      for (int k = 0; k < 11; k++) watt[k] *= sc;
      m = r;
    }
    float p = __expf(r - m);
    denom += p;
    #pragma unroll
    for (int k = 0; k < 11; k++) { float t = ev[k]; agg[k] += t * xs; watt[k] += (p * t) * xs; }
  }

  // merge the two halves
  float m_o = __shfl_xor(m, 32);
  float M = fmaxf(m, m_o);
  float ss = __expf(m - M);
  float so = __expf(m_o - M);
  float den_o = __shfl_xor(denom, 32);
  float denT = denom * ss + den_o * so;
  float inv = 1.f / (denT + 1e-16f);
  float comb[11];
  #pragma unroll
  for (int k = 0; k < 11; k++) {
    float ao = __shfl_xor(agg[k], 32);
    float wo = __shfl_xor(watt[k], 32);
    comb[k] = (agg[k] + ao) + (watt[k] * ss + wo * so) * inv;
  }

  if (half == 0) {
    bf16* arow = Abuf + (size_t)n * 352 + d * 11;
    #pragma unroll
    for (int k = 0; k < 11; k++) arow[k] = tob(comb[k]);
  }

  for (int j = lane; j < deg; j += 64) {
    int eid = elist[beg + j];
    atts[eid] = __expf(raw[eid] - M) * inv;
  }
}

// ---------------- conv einsum as MFMA GEMM: [N_PAD,352] x [352,32] ----------------
__global__ __launch_bounds__(256) void convgemm_kernel(const short* __restrict__ A, const short* __restrict__ Wt,
                                                       float* __restrict__ C) {
  int gid = blockIdx.x * blockDim.x + threadIdx.x;
  int wave = gid >> 6;
  int lane = threadIdx.x & 63;
  int r16 = lane & 15, kq = lane >> 4;
  int mbase = wave * 16;
  if (mbase >= N_PAD) return;
  const short* arow = A + (size_t)(mbase + r16) * 352 + kq * 8;
  bf16x8 af[11];
  #pragma unroll
  for (int ks = 0; ks < 11; ks++) af[ks] = *(const bf16x8*)(arow + ks * 32);
  const short* b0p = Wt + (size_t)r16 * 352 + kq * 8;
  const short* b1p = b0p + 16 * 352;
  f32x4v acc0 = {0.f, 0.f, 0.f, 0.f}, acc1 = {0.f, 0.f, 0.f, 0.f};
  #pragma unroll
  for (int ks = 0; ks < 11; ks++) {
    bf16x8 b0 = *(const bf16x8*)(b0p + ks * 32);
    bf16x8 b1 = *(const bf16x8*)(b1p + ks * 32);
    acc0 = __builtin_amdgcn_mfma_f32_16x16x32_bf16(af[ks], b0, acc0, 0, 0, 0);
    acc1 = __builtin_amdgcn_mfma_f32_16x16x32_bf16(af[ks], b1, acc1, 0, 0, 0);
  }
  float* crow = C + (size_t)(mbase + kq * 4) * 32 + r16;
  #pragma unroll
  for (int r = 0; r < 4; r++) {
    crow[(size_t)r * 32] = acc0[r];
    crow[(size_t)r * 32 + 16] = acc1[r];
  }
}

// ---------------- per-node epilogue ----------------
__global__ __launch_bounds__(256) void epilogue_kernel(const float* __restrict__ Cpre, const float* __restrict__ hp,
                                                       float* __restrict__ h,
                                                       const float* __restrict__ convb, const float* __restrict__ s1w,
                                                       const float* __restrict__ s1b, const float* __restrict__ s2w,
                                                       const float* __restrict__ s2b, const float* __restrict__ outw,
                                                       const float* __restrict__ outb, int N) {
  __shared__ float sow[1024], sob[32], scb[32], ss1[64], ss2[64], ssb[4];
  __shared__ float lout[8][33];
  for (int i = threadIdx.x; i < 1024; i += 256) sow[i] = outw[i];
  if (threadIdx.x < 32) { sob[threadIdx.x] = outb[threadIdx.x];
                          scb[threadIdx.x] = (threadIdx.x < 30) ? convb[threadIdx.x] : 0.f; }
  if (threadIdx.x >= 32 && threadIdx.x < 96)  ss1[threadIdx.x - 32] = s1w[threadIdx.x - 32];
  if (threadIdx.x >= 96 && threadIdx.x < 160) ss2[threadIdx.x - 96] = s2w[threadIdx.x - 96];
  if (threadIdx.x >= 160 && threadIdx.x < 162) ssb[threadIdx.x - 160] = s1b[threadIdx.x - 160];
  if (threadIdx.x >= 162 && threadIdx.x < 164) ssb[threadIdx.x - 160] = s2b[threadIdx.x - 162];
  __syncthreads();
  int grp = threadIdx.x >> 5, d = threadIdx.x & 31;
  int n = blockIdx.x * 8 + grp;
  bool valid = (n < N);
  float lo = 0.f;
  if (valid) {
    if (d < 30) {
      lo = fmaxf(Cpre[(size_t)n * 32 + d] + scb[d], 0.f);
    } else {
      int j = d - 30;
      float a1 = ssb[j], a2 = ssb[2 + j];
      const float* hr = hp + (size_t)n * 32;
      #pragma unroll
      for (int dd = 0; dd < 32; dd++) { float hv = hr[dd]; a1 += hv * ss1[dd*2 + j]; a2 += hv * ss2[dd*2 + j]; }
      lo = tanh_fast(a1) * tanh_fast(a2);
    }
  }
  lout[grp][d] = lo;
  __syncthreads();
  if (valid) {
    float acc = sob[d];
    #pragma unroll
    for (int j = 0; j < 32; j++) acc += lout[grp][j] * sow[j*32 + d];
    h[(size_t)n * 32 + d] += acc;
  }
}

// ---------------- global mean pool + final head ----------------
__global__ __launch_bounds__(256) void pool_kernel(const float* __restrict__ h, const int* __restrict__ batch,
                                                   float* __restrict__ gsum, int* __restrict__ gcnt,
                                                   float* __restrict__ outh, int N) {
  int i = blockIdx.x * blockDim.x + threadIdx.x;
  if (i >= N * 32) return;
  int n = i >> 5, d = i & 31;
  float v = h[i];
  outh[i] = v;
  int g = batch[n];
  atomicAdd(&gsum[g * 32 + d], v);
  if (d == 0) atomicAdd(&gcnt[g], 1);
}

__global__ __launch_bounds__(256) void final_kernel(const float* __restrict__ gsum, const int* __restrict__ gcnt,
                                                    const float* __restrict__ fw, const float* __restrict__ fb,
                                                    float* __restrict__ out0) {
  int i = blockIdx.x * blockDim.x + threadIdx.x;
  if (i >= N_GR * 32) return;
  int g = i >> 5, j = i & 31;
  float invc = 1.f / fmaxf((float)gcnt[g], 1.f);
  float acc = fb[j];
  const float* gr = gsum + (size_t)g * 32;
  #pragma unroll
  for (int dd = 0; dd < 32; dd++) acc += gr[dd] * invc * fw[dd*32 + j];
  out0[i] = acc;
}

extern "C" void kernel_launch(void* const* d_in, const int* in_sizes, int n_in,
                              void* d_out, int out_size, void* d_ws, size_t ws_size,
                              hipStream_t stream) {
  (void)in_sizes; (void)n_in; (void)out_size; (void)ws_size;
  const float* x      = (const float*)d_in[0];
  const float* eattr  = (const float*)d_in[1];
  const int* eidx     = (const int*)d_in[2];
  const int* batch    = (const int*)d_in[3];
  const float* emb_w  = (const float*)d_in[4];
  const float* emb_b  = (const float*)d_in[5];
  const float* init_w = (const float*)d_in[6];
  const float* e1w    = (const float*)d_in[7];
  const float* e2w    = (const float*)d_in[8];
  const float* e3w    = (const float*)d_in[9];
  const float* e4w    = (const float*)d_in[10];
  const float* convw  = (const float*)d_in[11];
  const float* convb  = (const float*)d_in[12];
  const float* attv   = (const float*)d_in[13];
  const float* s1w    = (const float*)d_in[14];
  const float* s1b    = (const float*)d_in[15];
  const float* s2w    = (const float*)d_in[16];
  const float* s2b    = (const float*)d_in[17];
  const float* outw   = (const float*)d_in[18];
  const float* outb   = (const float*)d_in[19];
  const float* finw   = (const float*)d_in[20];
  const float* finb   = (const float*)d_in[21];

  char* ws = (char*)d_ws;
  size_t off = 0;
  auto take = [&](size_t bytes) -> char* {
    char* p = ws + off;
    off += (bytes + 255) & ~(size_t)255;
    return p;
  };
  float* h    = (float*)take((size_t)N_NODES * 32 * 4);
  float* hp   = (float*)take((size_t)N_NODES * 32 * 4);
  float* eav  = (float*)take((size_t)N_EDGES * 12 * 4);
  float* raw  = (float*)take((size_t)N_EDGES * 4);
  bf16*  Abuf = (bf16*)take((size_t)N_PAD * 352 * 2);
  float* Cpre = (float*)take((size_t)N_PAD * 32 * 4);
  float* gsum = (float*)take((size_t)N_GR * 32 * 4);
  int*   gcnt = (int*)take((size_t)N_GR * 4);
  int*   deg  = (int*)take((size_t)N_NODES * 4);
  int*   offs = (int*)take((size_t)(N_NODES + 1) * 4);
  int*   cur  = (int*)take((size_t)N_NODES * 4);
  int*   elist= (int*)take((size_t)N_EDGES * 4);
  float* wE   = (float*)take((size_t)2 * 1352 * 4);
  bf16*  Wt   = (bf16*)take((size_t)2 * 32 * 352 * 2);

  float* out0 = (float*)d_out;
  float* outh = out0 + N_GR * 32;
  float* outa = outh + (size_t)N_NODES * 32;

  const int* srcA = eidx;
  const int* dstA = eidx + N_EDGES;

  hipMemsetAsync(deg, 0, (size_t)N_NODES * 4, stream);
  hipMemsetAsync(gsum, 0, (size_t)N_GR * 32 * 4, stream);
  hipMemsetAsync(gcnt, 0, (size_t)N_GR * 4, stream);

  prep_kernel<<<99, 256, 0, stream>>>(e1w, e2w, e3w, e4w, attv, convw, wE, Wt);
  hist_kernel<<<(N_EDGES + 255) / 256, 256, 0, stream>>>(dstA, deg, N_EDGES);
  scan_kernel<<<1, 1024, 0, stream>>>(deg, offs, cur, N_NODES);
  fill_kernel<<<(N_EDGES + 255) / 256, 256, 0, stream>>>(dstA, cur, elist, N_EDGES);
  emb_kernel<<<(N_NODES * 32 + 255) / 256, 256, 0, stream>>>(x, emb_w, emb_b, h, N_NODES);

  for (int l = 0; l < 2; l++) {
    hproj_kernel<<<(N_NODES * 32 + 255) / 256, 256, 0, stream>>>(h, init_w + l * 1024, hp, N_NODES);
    edge_kernel<<<(N_EDGES + 256 * EC - 1) / (256 * EC), 256, 0, stream>>>(
        eattr, srcA, hp, wE + l * 1352, eav, raw, N_EDGES);
    node_kernel<<<N_PAD / 4, 256, 0, stream>>>(offs, elist, srcA, (const float4*)eav, raw, hp,
                                               Abuf, outa + (size_t)l * N_EDGES, N_NODES);
    convgemm_kernel<<<(N_PAD / 16 * 64 + 255) / 256, 256, 0, stream>>>(
        (const short*)Abuf, (const short*)Wt + (size_t)l * 32 * 352, Cpre);
    epilogue_kernel<<<(N_NODES + 7) / 8, 256, 0, stream>>>(Cpre, hp, h,
        convb + l * 30, s1w + l * 64, s1b + l * 2, s2w + l * 64, s2b + l * 2,
        outw + l * 1024, outb + l * 32, N_NODES);
  }

  pool_kernel<<<(N_NODES * 32 + 255) / 256, 256, 0, stream>>>(h, batch, gsum, gcnt, outh, N_NODES);
  final_kernel<<<(N_GR * 32 + 255) / 256, 256, 0, stream>>>(gsum, gcnt, finw, finb, out0);
}

// Round 3
// 336.967 us; speedup vs baseline: 1.3134x; 1.3134x over previous
//
#include <hip/hip_runtime.h>
#include <hip/hip_bf16.h>

typedef __hip_bfloat16 bf16;
using f32x4v = __attribute__((ext_vector_type(4))) float;
using bf16x8 = __attribute__((ext_vector_type(8))) short;

#define N_NODES 25000
#define N_PAD   25024   // multiple of 64 for fused conv kernel
#define N_EDGES 400000
#define N_GR    100
#define EC 4

__device__ __forceinline__ bf16 tob(float v) { return __float2bfloat16(v); }
__device__ __forceinline__ unsigned short tobu(float v) {
  union { bf16 b; unsigned short u; } c; c.b = __float2bfloat16(v); return c.u;
}
__device__ __forceinline__ float b2f(unsigned short u) { return __uint_as_float(((unsigned)u) << 16); }
__device__ __forceinline__ float tanh_fast(float x) {
  float cx = fminf(fmaxf(x, -10.f), 10.f);
  float e = __expf(2.f * cx);
  return (e - 1.f) / (e + 1.f);
}

// ---------------- CSR build ----------------
__global__ __launch_bounds__(256) void hist_kernel(const int* __restrict__ dst, int* __restrict__ deg, int E) {
  int e = blockIdx.x * blockDim.x + threadIdx.x;
  if (e < E) atomicAdd(&deg[dst[e]], 1);
}

__global__ __launch_bounds__(1024) void scan_kernel(const int* __restrict__ deg, int* __restrict__ offs,
                                                    int* __restrict__ cur, int n) {
  __shared__ int wsum[16];
  __shared__ int wpre[16];
  int t = threadIdx.x, lane = t & 63, w = t >> 6;
  int carry = 0;
  for (int base = 0; base < n; base += 1024) {
    int v = (base + t < n) ? deg[base + t] : 0;
    int x = v;
    #pragma unroll
    for (int s = 1; s < 64; s <<= 1) { int y = __shfl_up(x, s); if (lane >= s) x += y; }
    if (lane == 63) wsum[w] = x;
    __syncthreads();
    if (w == 0 && lane < 16) {
      int ws_ = wsum[lane];
      int xs = ws_;
      #pragma unroll
      for (int s = 1; s < 16; s <<= 1) { int y = __shfl_up(xs, s); if (lane >= s) xs += y; }
      wpre[lane] = xs - ws_;
    }
    __syncthreads();
    int excl = carry + wpre[w] + x - v;
    if (base + t < n) { offs[base + t] = excl; cur[base + t] = excl; }
    carry += wpre[15] + wsum[15];
    __syncthreads();
  }
  if (t == 0) offs[n] = carry;
}

__global__ __launch_bounds__(256) void fill_kernel(const int* __restrict__ dst, int* __restrict__ cur,
                                                   int* __restrict__ elist, int E) {
  int e = blockIdx.x * blockDim.x + threadIdx.x;
  if (e < E) { int p = atomicAdd(&cur[dst[e]], 1); elist[p] = e; }
}

// ---------------- weight prep ----------------
// wE per layer (1352 f32): [e1t 22x12][e2t 22x12][e3t 22x12][e4L 22x12][e4G 22x12][attv 32]
// Wt  per layer (32x352 bf16): Wt[o][d*11+kk] = conv_w[kk][d][o]  (o>=30 zero)
// owB per layer (2x64x8 bf16): owB[hf][lane][j] = outw[k*32 + hf*16 + n], k=(lane>>4)*8+j, n=lane&15
__global__ __launch_bounds__(256) void prep_kernel(const float* __restrict__ e1, const float* __restrict__ e2,
                                                   const float* __restrict__ e3, const float* __restrict__ e4,
                                                   const float* __restrict__ attv, const float* __restrict__ convw,
                                                   const float* __restrict__ outw,
                                                   float* __restrict__ wE, bf16* __restrict__ Wt,
                                                   bf16* __restrict__ owB) {
  int i = blockIdx.x * blockDim.x + threadIdx.x;
  if (i < 2 * 1352) {
    int l = i / 1352, r = i % 1352;
    float v = 0.f;
    if (r < 264)       { int q = r;        int j = q / 12, k = q % 12; if (k < 11) v = e1[l*242 + k*22 + j]; }
    else if (r < 528)  { int q = r - 264;  int j = q / 12, k = q % 12; if (k < 11) v = e2[l*242 + k*22 + j]; }
    else if (r < 792)  { int q = r - 528;  int j = q / 12, k = q % 12; if (k < 11) v = e3[l*242 + k*22 + j]; }
    else if (r < 1056) { int q = r - 792;  int j = q / 12, k = q % 12; if (k < 11) v = e4[l*484 + j*11 + k]; }
    else if (r < 1320) { int q = r - 1056; int j = q / 12, k = q % 12; if (k < 11) v = e4[l*484 + (22 + j)*11 + k]; }
    else               { int d = r - 1320; v = attv[l*32 + d]; }
    wE[i] = v;
  }
  int t = i - 2 * 1352;
  if (t >= 0 && t < 2 * 32 * 352) {
    int l = t / (32 * 352), q = t % (32 * 352);
    int o = q / 352, dk = q % 352;
    int d = dk / 11, kk = dk % 11;
    float v = 0.f;
    if (o < 30) v = convw[l*10560 + (kk*32 + d)*30 + o];
    Wt[t] = tob(v);
  }
  int u = i - 2 * 1352 - 2 * 32 * 352;
  if (u >= 0 && u < 2048) {
    int l = u >> 10, rem = u & 1023;
    int hf = rem >> 9, rem2 = rem & 511;
    int lane = rem2 >> 3, j = rem2 & 7;
    int k = (lane >> 4) * 8 + j, n = lane & 15;
    owB[u] = tob(outw[l*1024 + k*32 + hf*16 + n]);
  }
}

// ---------------- embedding / h_proj ----------------
__global__ __launch_bounds__(256) void emb_kernel(const float* __restrict__ x, const float* __restrict__ w,
                                                  const float* __restrict__ b, float* __restrict__ h, int N) {
  __shared__ float sw[16 * 32];
  __shared__ float sb[32];
  for (int i = threadIdx.x; i < 16 * 32; i += blockDim.x) sw[i] = w[i];
  if (threadIdx.x < 32) sb[threadIdx.x] = b[threadIdx.x];
  __syncthreads();
  int i = blockIdx.x * blockDim.x + threadIdx.x;
  if (i >= N * 32) return;
  int n = i >> 5, d = i & 31;
  float acc = sb[d];
  #pragma unroll
  for (int k = 0; k < 16; k++) acc += x[n*16 + k] * sw[k*32 + d];
  h[i] = acc;
}

__global__ __launch_bounds__(256) void hproj_kernel(const float* __restrict__ h, const float* __restrict__ w,
                                                    float* __restrict__ hp, unsigned short* __restrict__ hpb, int N) {
  __shared__ float sw[32 * 32];
  for (int i = threadIdx.x; i < 32 * 32; i += blockDim.x) sw[i] = w[i];
  __syncthreads();
  int i = blockIdx.x * blockDim.x + threadIdx.x;
  if (i >= N * 32) return;
  int n = i >> 5, d = i & 31;
  const float* hr = h + (size_t)n * 32;
  float acc = 0.f;
  #pragma unroll
  for (int k = 0; k < 32; k++) acc += hr[k] * sw[k*32 + d];
  hp[i] = acc;
  hpb[i] = tobu(acc);
}

// ---------------- edge MLP + raw attention ----------------
__device__ __forceinline__ void loadw12(const float4* base, int idx3, float* w) {
  float4 a = base[idx3], b = base[idx3 + 1], c = base[idx3 + 2];
  w[0]=a.x; w[1]=a.y; w[2]=a.z; w[3]=a.w;
  w[4]=b.x; w[5]=b.y; w[6]=b.z; w[7]=b.w;
  w[8]=c.x; w[9]=c.y; w[10]=c.z; w[11]=c.w;
}

__global__ __launch_bounds__(256) void edge_kernel(const float* __restrict__ eattr,
                                                   const int* __restrict__ srcA, const float* __restrict__ hp,
                                                   const float* __restrict__ wEl,
                                                   uint2* __restrict__ eab, float* __restrict__ raw_out, int E) {
  const float4* w4 = (const float4*)wEl;
  int e0 = blockIdx.x * (blockDim.x * EC) + threadIdx.x;
  int e[EC]; bool live[EC];
  float a[EC][11], acc[EC][11];
  #pragma unroll
  for (int c = 0; c < EC; c++) {
    e[c] = e0 + c * blockDim.x;
    live[c] = e[c] < E;
    #pragma unroll
    for (int k = 0; k < 11; k++) {
      a[c][k] = live[c] ? eattr[(size_t)e[c]*11 + k] : 0.f;
      acc[c][k] = 0.f;
    }
  }
  for (int j = 0; j < 22; j++) {
    float w[12], l1[EC], l2[EC], gg[EC];
    loadw12(w4, j*3, w);
    #pragma unroll
    for (int c = 0; c < EC; c++) { float s = 0.f;
      #pragma unroll
      for (int k = 0; k < 11; k++) s += a[c][k] * w[k];
      l1[c] = s; }
    loadw12(w4, 66 + j*3, w);
    #pragma unroll
    for (int c = 0; c < EC; c++) { float s = 0.f;
      #pragma unroll
      for (int k = 0; k < 11; k++) s += a[c][k] * w[k];
      l2[c] = s; }
    loadw12(w4, 132 + j*3, w);
    #pragma unroll
    for (int c = 0; c < EC; c++) { float s = 0.f;
      #pragma unroll
      for (int k = 0; k < 11; k++) s += a[c][k] * w[k];
      gg[c] = tanh_fast(l2[c]) * tanh_fast(s);
      l1[c] = fmaxf(l1[c], 0.f); }
    float wl[12], wg[12];
    loadw12(w4, 198 + j*3, wl);
    loadw12(w4, 264 + j*3, wg);
    #pragma unroll
    for (int c = 0; c < EC; c++) {
      #pragma unroll
      for (int k = 0; k < 11; k++) acc[c][k] += l1[c]*wl[k] + gg[c]*wg[k];
    }
  }
  const float* av = wEl + 1320;
  #pragma unroll
  for (int c = 0; c < EC; c++) {
    if (!live[c]) continue;
    float mean = 0.f;
    #pragma unroll
    for (int k = 0; k < 11; k++) { acc[c][k] = fmaxf(acc[c][k], 0.f); mean += acc[c][k]; }
    mean *= (1.f / 11.f);
    unsigned p[6];
    #pragma unroll
    for (int q = 0; q < 5; q++)
      p[q] = (unsigned)tobu(acc[c][2*q]) | ((unsigned)tobu(acc[c][2*q+1]) << 16);
    p[5] = (unsigned)tobu(acc[c][10]);
    uint2* er = eab + (size_t)e[c] * 3;
    er[0] = make_uint2(p[0], p[1]);
    er[1] = make_uint2(p[2], p[3]);
    er[2] = make_uint2(p[4], p[5]);
    int s = srcA[e[c]];
    const float4* hp4 = (const float4*)(hp + (size_t)s * 32);
    float dot = 0.f;
    #pragma unroll
    for (int q = 0; q < 8; q++) {
      float4 hv = hp4[q];
      dot += hv.x*av[q*4+0] + hv.y*av[q*4+1] + hv.z*av[q*4+2] + hv.w*av[q*4+3];
    }
    raw_out[e[c]] = mean * dot;
  }
}

// ---------------- per-node aggregation with online segment softmax ----------------
__global__ __launch_bounds__(256) void node_kernel(const int* __restrict__ offs, const int* __restrict__ elist,
                                                   const int* __restrict__ srcA,
                                                   const uint2* __restrict__ eab, const float* __restrict__ raw,
                                                   const unsigned short* __restrict__ hpb,
                                                   bf16* __restrict__ Abuf, float* __restrict__ atts, int N) {
  int wid = threadIdx.x >> 6, lane = threadIdx.x & 63;
  int half = lane >> 5, d = lane & 31;
  int n = blockIdx.x * 4 + wid;
  if (n >= N_PAD) return;
  bool valid = (n < N);
  int beg = 0, deg = 0;
  if (valid) { beg = offs[n]; deg = offs[n + 1] - beg; }

  float agg[11], watt[11];
  #pragma unroll
  for (int k = 0; k < 11; k++) { agg[k] = 0.f; watt[k] = 0.f; }
  float m = -1e30f, denom = 0.f;

  for (int j = half; j < deg; j += 2) {
    int eid = elist[beg + j];
    int s = srcA[eid];
    float xs = b2f(hpb[(size_t)s * 32 + d]);
    float r = raw[eid];
    uint2 q0 = eab[(size_t)eid * 3 + 0];
    uint2 q1 = eab[(size_t)eid * 3 + 1];
    uint2 q2 = eab[(size_t)eid * 3 + 2];
    float ev[11];
    ev[0] = b2f((unsigned short)q0.x); ev[1] = b2f((unsigned short)(q0.x >> 16));
    ev[2] = b2f((unsigned short)q0.y); ev[3] = b2f((unsigned short)(q0.y >> 16));
    ev[4] = b2f((unsigned short)q1.x); ev[5] = b2f((unsigned short)(q1.x >> 16));
    ev[6] = b2f((unsigned short)q1.y); ev[7] = b2f((unsigned short)(q1.y >> 16));
    ev[8] = b2f((unsigned short)q2.x); ev[9] = b2f((unsigned short)(q2.x >> 16));
    ev[10] = b2f((unsigned short)q2.y);
    if (r > m) {
      float sc = __expf(m - r);
      denom *= sc;
      #pragma unroll
      for (int k = 0; k < 11; k++) watt[k] *= sc;
      m = r;
    }
    float p = __expf(r - m);
    denom += p;
    #pragma unroll
    for (int k = 0; k < 11; k++) { float t = ev[k]; agg[k] += t * xs; watt[k] += (p * t) * xs; }
  }

  // merge the two halves
  float m_o = __shfl_xor(m, 32);
  float M = fmaxf(m, m_o);
  float ss = __expf(m - M);
  float so = __expf(m_o - M);
  float den_o = __shfl_xor(denom, 32);
  float denT = denom * ss + den_o * so;
  float inv = 1.f / (denT + 1e-16f);
  float comb[11];
  #pragma unroll
  for (int k = 0; k < 11; k++) {
    float ao = __shfl_xor(agg[k], 32);
    float wo = __shfl_xor(watt[k], 32);
    comb[k] = (agg[k] + ao) + (watt[k] * ss + wo * so) * inv;
  }

  if (half == 0) {
    bf16* arow = Abuf + (size_t)n * 352 + d * 11;
    #pragma unroll
    for (int k = 0; k < 11; k++) arow[k] = tob(comb[k]);
  }

  for (int j = lane; j < deg; j += 64) {
    int eid = elist[beg + j];
    atts[eid] = __expf(raw[eid] - M) * inv;
  }
}

// ---------------- fused conv GEMM + epilogue ----------------
// block = 256 (4 waves, 64 rows). D1 = A[64,352]@Wt^T -> relu/skip -> D2 = lo@outw -> h +=
__global__ __launch_bounds__(256) void convfused_kernel(const short* __restrict__ A, const short* __restrict__ Wt,
                                                        const short* __restrict__ owB,
                                                        const float* __restrict__ hp, float* __restrict__ h,
                                                        const float* __restrict__ convb,
                                                        const float* __restrict__ s1w, const float* __restrict__ s1b,
                                                        const float* __restrict__ s2w, const float* __restrict__ s2b,
                                                        const float* __restrict__ outb, int N) {
  __shared__ short slo[64][40];     // layer_out bf16, padded (16B-aligned rows)
  __shared__ float sdelta[64][36];  // delta f32, padded
  __shared__ float sskipw[128];     // ss1[64], ss2[64]
  __shared__ float sskipb[4];
  __shared__ float scb[32];
  __shared__ float sob[32];
  int tid = threadIdx.x;
  if (tid < 64) sskipw[tid] = s1w[tid];
  if (tid >= 64 && tid < 128) sskipw[tid] = s2w[tid - 64];
  if (tid >= 128 && tid < 160) sob[tid - 128] = outb[tid - 128];
  if (tid >= 160 && tid < 192) scb[tid - 160] = (tid - 160 < 30) ? convb[tid - 160] : 0.f;
  if (tid >= 192 && tid < 196) sskipb[tid - 192] = (tid < 194) ? s1b[tid - 192] : s2b[tid - 194];
  __syncthreads();

  int wave = tid >> 6, lane = tid & 63;
  int r16 = lane & 15, kq = lane >> 4;
  int mbase = blockIdx.x * 64 + wave * 16;

  // ---- MFMA1: conv einsum ----
  const short* arow = A + (size_t)(mbase + r16) * 352 + kq * 8;
  const short* b0p = Wt + (size_t)r16 * 352 + kq * 8;
  const short* b1p = b0p + 16 * 352;
  f32x4v acc0 = {0.f, 0.f, 0.f, 0.f}, acc1 = {0.f, 0.f, 0.f, 0.f};
  #pragma unroll
  for (int ks = 0; ks < 11; ks++) {
    bf16x8 af = *(const bf16x8*)(arow + ks * 32);
    bf16x8 b0 = *(const bf16x8*)(b0p + ks * 32);
    bf16x8 b1 = *(const bf16x8*)(b1p + ks * 32);
    acc0 = __builtin_amdgcn_mfma_f32_16x16x32_bf16(af, b0, acc0, 0, 0, 0);
    acc1 = __builtin_amdgcn_mfma_f32_16x16x32_bf16(af, b1, acc1, 0, 0, 0);
  }
  // write relu(conv + bias) to LDS (cols 0..29); cols 30,31 filled by skip threads
  #pragma unroll
  for (int r = 0; r < 4; r++) {
    int row = wave * 16 + kq * 4 + r;
    slo[row][r16] = (short)tobu(fmaxf(acc0[r] + scb[r16], 0.f));
    if (r16 < 14) slo[row][16 + r16] = (short)tobu(fmaxf(acc1[r] + scb[16 + r16], 0.f));
  }
  __syncthreads();

  // ---- skip gates for cols 30,31 ----
  if (tid < 128) {
    int row = tid >> 1, j = tid & 1;
    int grow = blockIdx.x * 64 + row;
    float a1 = sskipb[j], a2 = sskipb[2 + j];
    if (grow < N) {
      const float* hr = hp + (size_t)grow * 32;
      #pragma unroll
      for (int dd = 0; dd < 32; dd++) {
        float hv = hr[dd];
        a1 += hv * sskipw[dd*2 + j];
        a2 += hv * sskipw[64 + dd*2 + j];
      }
    }
    slo[row][30 + j] = (short)tobu(tanh_fast(a1) * tanh_fast(a2));
  }
  __syncthreads();

  // ---- MFMA2: delta = lo @ outw ----
  bf16x8 a2f = *(const bf16x8*)&slo[wave * 16 + r16][kq * 8];
  bf16x8 bo0 = *(const bf16x8*)(owB + lane * 8);
  bf16x8 bo1 = *(const bf16x8*)(owB + 512 + lane * 8);
  f32x4v d0 = {0.f, 0.f, 0.f, 0.f}, d1 = {0.f, 0.f, 0.f, 0.f};
  d0 = __builtin_amdgcn_mfma_f32_16x16x32_bf16(a2f, bo0, d0, 0, 0, 0);
  d1 = __builtin_amdgcn_mfma_f32_16x16x32_bf16(a2f, bo1, d1, 0, 0, 0);
  #pragma unroll
  for (int r = 0; r < 4; r++) {
    int row = wave * 16 + kq * 4 + r;
    sdelta[row][r16] = d0[r] + sob[r16];
    sdelta[row][16 + r16] = d1[r] + sob[16 + r16];
  }
  __syncthreads();

  // ---- h += delta (coalesced) ----
  {
    int row = tid >> 2, col0 = (tid & 3) * 8;
    int grow = blockIdx.x * 64 + row;
    if (grow < N) {
      float* hr = h + (size_t)grow * 32 + col0;
      float4 ha = *(float4*)hr;
      float4 hb = *(float4*)(hr + 4);
      float4 da = *(float4*)&sdelta[row][col0];
      float4 db = *(float4*)&sdelta[row][col0 + 4];
      ha.x += da.x; ha.y += da.y; ha.z += da.z; ha.w += da.w;
      hb.x += db.x; hb.y += db.y; hb.z += db.z; hb.w += db.w;
      *(float4*)hr = ha;
      *(float4*)(hr + 4) = hb;
    }
  }
}

// ---------------- graph bounds + fused pool / outh / final head ----------------
__global__ void bounds_kernel(const int* __restrict__ batch, int* __restrict__ gb) {
  int g = threadIdx.x;
  if (g > N_GR) return;
  if (g == N_GR) { gb[g] = N_NODES; return; }
  int lo = 0, hi = N_NODES;
  while (lo < hi) { int mid = (lo + hi) >> 1; if (batch[mid] < g) lo = mid + 1; else hi = mid; }
  gb[g] = lo;
}

__global__ __launch_bounds__(256) void pool2_kernel(const float* __restrict__ h, const int* __restrict__ gb,
                                                    const float* __restrict__ fw, const float* __restrict__ fb,
                                                    float* __restrict__ out0, float* __restrict__ outh) {
  __shared__ float part[8][32];
  __shared__ float pooled[32];
  int g = blockIdx.x;
  int s = gb[g], e = gb[g + 1];
  int grp = threadIdx.x >> 5, d = threadIdx.x & 31;
  float acc = 0.f;
  for (int n = s + grp; n < e; n += 8) {
    float v = h[(size_t)n * 32 + d];
    outh[(size_t)n * 32 + d] = v;
    acc += v;
  }
  part[grp][d] = acc;
  __syncthreads();
  if (threadIdx.x < 32) {
    float sum = 0.f;
    #pragma unroll
    for (int i = 0; i < 8; i++) sum += part[i][d];
    pooled[d] = sum / fmaxf((float)(e - s), 1.f);
  }
  __syncthreads();
  if (threadIdx.x < 32) {
    int j = threadIdx.x;
    float o = fb[j];
    #pragma unroll
    for (int dd = 0; dd < 32; dd++) o += pooled[dd] * fw[dd*32 + j];
    out0[g * 32 + j] = o;
  }
}

extern "C" void kernel_launch(void* const* d_in, const int* in_sizes, int n_in,
                              void* d_out, int out_size, void* d_ws, size_t ws_size,
                              hipStream_t stream) {
  (void)in_sizes; (void)n_in; (void)out_size; (void)ws_size;
  const float* x      = (const float*)d_in[0];
  const float* eattr  = (const float*)d_in[1];
  const int* eidx     = (const int*)d_in[2];
  const int* batch    = (const int*)d_in[3];
  const float* emb_w  = (const float*)d_in[4];
  const float* emb_b  = (const float*)d_in[5];
  const float* init_w = (const float*)d_in[6];
  const float* e1w    = (const float*)d_in[7];
  const float* e2w    = (const float*)d_in[8];
  const float* e3w    = (const float*)d_in[9];
  const float* e4w    = (const float*)d_in[10];
  const float* convw  = (const float*)d_in[11];
  const float* convb  = (const float*)d_in[12];
  const float* attv   = (const float*)d_in[13];
  const float* s1w    = (const float*)d_in[14];
  const float* s1b    = (const float*)d_in[15];
  const float* s2w    = (const float*)d_in[16];
  const float* s2b    = (const float*)d_in[17];
  const float* outw   = (const float*)d_in[18];
  const float* outb   = (const float*)d_in[19];
  const float* finw   = (const float*)d_in[20];
  const float* finb   = (const float*)d_in[21];

  char* ws = (char*)d_ws;
  size_t off = 0;
  auto take = [&](size_t bytes) -> char* {
    char* p = ws + off;
    off += (bytes + 255) & ~(size_t)255;
    return p;
  };
  float* h    = (float*)take((size_t)N_NODES * 32 * 4);
  float* hp   = (float*)take((size_t)N_NODES * 32 * 4);
  unsigned short* hpb = (unsigned short*)take((size_t)N_NODES * 32 * 2);
  uint2* eab  = (uint2*)take((size_t)N_EDGES * 24);
  float* raw  = (float*)take((size_t)N_EDGES * 4);
  bf16*  Abuf = (bf16*)take((size_t)N_PAD * 352 * 2);
  int*   deg  = (int*)take((size_t)N_NODES * 4);
  int*   offs = (int*)take((size_t)(N_NODES + 1) * 4);
  int*   cur  = (int*)take((size_t)N_NODES * 4);
  int*   elist= (int*)take((size_t)N_EDGES * 4);
  int*   gb   = (int*)take((size_t)(N_GR + 1) * 4);
  float* wE   = (float*)take((size_t)2 * 1352 * 4);
  bf16*  Wt   = (bf16*)take((size_t)2 * 32 * 352 * 2);
  bf16*  owB  = (bf16*)take((size_t)2048 * 2);

  float* out0 = (float*)d_out;
  float* outh = out0 + N_GR * 32;
  float* outa = outh + (size_t)N_NODES * 32;

  const int* srcA = eidx;
  const int* dstA = eidx + N_EDGES;

  hipMemsetAsync(deg, 0, (size_t)N_NODES * 4, stream);

  prep_kernel<<<107, 256, 0, stream>>>(e1w, e2w, e3w, e4w, attv, convw, outw, wE, Wt, owB);
  hist_kernel<<<(N_EDGES + 255) / 256, 256, 0, stream>>>(dstA, deg, N_EDGES);
  scan_kernel<<<1, 1024, 0, stream>>>(deg, offs, cur, N_NODES);
  fill_kernel<<<(N_EDGES + 255) / 256, 256, 0, stream>>>(dstA, cur, elist, N_EDGES);
  emb_kernel<<<(N_NODES * 32 + 255) / 256, 256, 0, stream>>>(x, emb_w, emb_b, h, N_NODES);
  bounds_kernel<<<1, 128, 0, stream>>>(batch, gb);

  for (int l = 0; l < 2; l++) {
    hproj_kernel<<<(N_NODES * 32 + 255) / 256, 256, 0, stream>>>(h, init_w + l * 1024, hp, hpb, N_NODES);
    edge_kernel<<<(N_EDGES + 256 * EC - 1) / (256 * EC), 256, 0, stream>>>(
        eattr, srcA, hp, wE + l * 1352, eab, raw, N_EDGES);
    node_kernel<<<N_PAD / 4, 256, 0, stream>>>(offs, elist, srcA, eab, raw, hpb,
                                               Abuf, outa + (size_t)l * N_EDGES, N_NODES);
    convfused_kernel<<<N_PAD / 64, 256, 0, stream>>>(
        (const short*)Abuf, (const short*)Wt + (size_t)l * 32 * 352, (const short*)owB + (size_t)l * 1024,
        hp, h, convb + l * 30, s1w + l * 64, s1b + l * 2, s2w + l * 64, s2b + l * 2,
        outb + l * 32, N_NODES);
  }

  pool2_kernel<<<N_GR, 256, 0, stream>>>(h, gb, finw, finb, out0, outh);
}

// Round 4
// 277.267 us; speedup vs baseline: 1.5962x; 1.2153x over previous
//
#include <hip/hip_runtime.h>
#include <hip/hip_bf16.h>

typedef __hip_bfloat16 bf16;
using f32x4v = __attribute__((ext_vector_type(4))) float;
using bf16x8 = __attribute__((ext_vector_type(8))) short;

#define N_NODES 25000
#define N_PAD   25024   // multiple of 64 for fused conv kernel
#define N_EDGES 400000
#define N_GR    100

__device__ __forceinline__ bf16 tob(float v) { return __float2bfloat16(v); }
__device__ __forceinline__ unsigned short tobu(float v) {
  union { bf16 b; unsigned short u; } c; c.b = __float2bfloat16(v); return c.u;
}
__device__ __forceinline__ float b2f(unsigned short u) { return __uint_as_float(((unsigned)u) << 16); }
__device__ __forceinline__ float tanh_fast(float x) {
  float cx = fminf(fmaxf(x, -10.f), 10.f);
  float e = __expf(2.f * cx);
  return (e - 1.f) / (e + 1.f);
}

// ---------------- CSR build ----------------
__global__ __launch_bounds__(256) void hist_kernel(const int* __restrict__ dst, int* __restrict__ deg, int E) {
  int e = blockIdx.x * blockDim.x + threadIdx.x;
  if (e < E) atomicAdd(&deg[dst[e]], 1);
}

__global__ __launch_bounds__(1024) void scan_kernel(const int* __restrict__ deg, int* __restrict__ offs,
                                                    int* __restrict__ cur, int n) {
  __shared__ int wsum[16];
  __shared__ int wpre[16];
  int t = threadIdx.x, lane = t & 63, w = t >> 6;
  int carry = 0;
  for (int base = 0; base < n; base += 1024) {
    int v = (base + t < n) ? deg[base + t] : 0;
    int x = v;
    #pragma unroll
    for (int s = 1; s < 64; s <<= 1) { int y = __shfl_up(x, s); if (lane >= s) x += y; }
    if (lane == 63) wsum[w] = x;
    __syncthreads();
    if (w == 0 && lane < 16) {
      int ws_ = wsum[lane];
      int xs = ws_;
      #pragma unroll
      for (int s = 1; s < 16; s <<= 1) { int y = __shfl_up(xs, s); if (lane >= s) xs += y; }
      wpre[lane] = xs - ws_;
    }
    __syncthreads();
    int excl = carry + wpre[w] + x - v;
    if (base + t < n) { offs[base + t] = excl; cur[base + t] = excl; }
    carry += wpre[15] + wsum[15];
    __syncthreads();
  }
  if (t == 0) offs[n] = carry;
}

__global__ __launch_bounds__(256) void fill_kernel(const int* __restrict__ dst, int* __restrict__ cur,
                                                   int* __restrict__ elist, int E) {
  int e = blockIdx.x * blockDim.x + threadIdx.x;
  if (e < E) { int p = atomicAdd(&cur[dst[e]], 1); elist[p] = e; }
}

// ---------------- weight prep ----------------
// wE per layer (1352 f32): [e1t 22x12][e2t 22x12][e3t 22x12][e4L 22x12][e4G 22x12][attv 32]
// Wt  per layer (32x352 bf16): Wt[o][d*11+kk] = conv_w[kk][d][o]  (o>=30 zero)
// owB per layer (2x64x8 bf16): owB[hf][lane][j] = outw[k*32 + hf*16 + n], k=(lane>>4)*8+j, n=lane&15
__global__ __launch_bounds__(256) void prep_kernel(const float* __restrict__ e1, const float* __restrict__ e2,
                                                   const float* __restrict__ e3, const float* __restrict__ e4,
                                                   const float* __restrict__ attv, const float* __restrict__ convw,
                                                   const float* __restrict__ outw,
                                                   float* __restrict__ wE, bf16* __restrict__ Wt,
                                                   bf16* __restrict__ owB) {
  int i = blockIdx.x * blockDim.x + threadIdx.x;
  if (i < 2 * 1352) {
    int l = i / 1352, r = i % 1352;
    float v = 0.f;
    if (r < 264)       { int q = r;        int j = q / 12, k = q % 12; if (k < 11) v = e1[l*242 + k*22 + j]; }
    else if (r < 528)  { int q = r - 264;  int j = q / 12, k = q % 12; if (k < 11) v = e2[l*242 + k*22 + j]; }
    else if (r < 792)  { int q = r - 528;  int j = q / 12, k = q % 12; if (k < 11) v = e3[l*242 + k*22 + j]; }
    else if (r < 1056) { int q = r - 792;  int j = q / 12, k = q % 12; if (k < 11) v = e4[l*484 + j*11 + k]; }
    else if (r < 1320) { int q = r - 1056; int j = q / 12, k = q % 12; if (k < 11) v = e4[l*484 + (22 + j)*11 + k]; }
    else               { int d = r - 1320; v = attv[l*32 + d]; }
    wE[i] = v;
  }
  int t = i - 2 * 1352;
  if (t >= 0 && t < 2 * 32 * 352) {
    int l = t / (32 * 352), q = t % (32 * 352);
    int o = q / 352, dk = q % 352;
    int d = dk / 11, kk = dk % 11;
    float v = 0.f;
    if (o < 30) v = convw[l*10560 + (kk*32 + d)*30 + o];
    Wt[t] = tob(v);
  }
  int u = i - 2 * 1352 - 2 * 32 * 352;
  if (u >= 0 && u < 2048) {
    int l = u >> 10, rem = u & 1023;
    int hf = rem >> 9, rem2 = rem & 511;
    int lane = rem2 >> 3, j = rem2 & 7;
    int k = (lane >> 4) * 8 + j, n = lane & 15;
    owB[u] = tob(outw[l*1024 + k*32 + hf*16 + n]);
  }
}

// ---------------- embedding / h_proj ----------------
__global__ __launch_bounds__(256) void emb_kernel(const float* __restrict__ x, const float* __restrict__ w,
                                                  const float* __restrict__ b, float* __restrict__ h, int N) {
  __shared__ float sw[16 * 32];
  __shared__ float sb[32];
  for (int i = threadIdx.x; i < 16 * 32; i += blockDim.x) sw[i] = w[i];
  if (threadIdx.x < 32) sb[threadIdx.x] = b[threadIdx.x];
  __syncthreads();
  int i = blockIdx.x * blockDim.x + threadIdx.x;
  if (i >= N * 32) return;
  int n = i >> 5, d = i & 31;
  float acc = sb[d];
  #pragma unroll
  for (int k = 0; k < 16; k++) acc += x[n*16 + k] * sw[k*32 + d];
  h[i] = acc;
}

__global__ __launch_bounds__(256) void hproj_kernel(const float* __restrict__ h, const float* __restrict__ w,
                                                    float* __restrict__ hp, unsigned short* __restrict__ hpb, int N) {
  __shared__ float sw[32 * 32];
  for (int i = threadIdx.x; i < 32 * 32; i += blockDim.x) sw[i] = w[i];
  __syncthreads();
  int i = blockIdx.x * blockDim.x + threadIdx.x;
  if (i >= N * 32) return;
  int n = i >> 5, d = i & 31;
  const float* hr = h + (size_t)n * 32;
  float acc = 0.f;
  #pragma unroll
  for (int k = 0; k < 32; k++) acc += hr[k] * sw[k*32 + d];
  hp[i] = acc;
  hpb[i] = tobu(acc);
}

// ---------------- edge MLP + raw attention (1 edge/thread for occupancy) ----------------
__device__ __forceinline__ void loadw12(const float4* base, int idx3, float* w) {
  float4 a = base[idx3], b = base[idx3 + 1], c = base[idx3 + 2];
  w[0]=a.x; w[1]=a.y; w[2]=a.z; w[3]=a.w;
  w[4]=b.x; w[5]=b.y; w[6]=b.z; w[7]=b.w;
  w[8]=c.x; w[9]=c.y; w[10]=c.z; w[11]=c.w;
}

__global__ __launch_bounds__(256) void edge_kernel(const float* __restrict__ eattr,
                                                   const int* __restrict__ srcA,
                                                   const unsigned short* __restrict__ hpb,
                                                   const float* __restrict__ wEl,
                                                   uint2* __restrict__ eab, float* __restrict__ raw_out, int E) {
  const float4* w4 = (const float4*)wEl;
  int e = blockIdx.x * blockDim.x + threadIdx.x;
  bool live = e < E;
  float a[11], acc[11];
  #pragma unroll
  for (int k = 0; k < 11; k++) {
    a[k] = live ? eattr[(size_t)e*11 + k] : 0.f;
    acc[k] = 0.f;
  }
  for (int j = 0; j < 22; j++) {
    float w[12];
    loadw12(w4, j*3, w);
    float l1 = 0.f;
    #pragma unroll
    for (int k = 0; k < 11; k++) l1 += a[k] * w[k];
    loadw12(w4, 66 + j*3, w);
    float l2 = 0.f;
    #pragma unroll
    for (int k = 0; k < 11; k++) l2 += a[k] * w[k];
    loadw12(w4, 132 + j*3, w);
    float l3 = 0.f;
    #pragma unroll
    for (int k = 0; k < 11; k++) l3 += a[k] * w[k];
    float gg = tanh_fast(l2) * tanh_fast(l3);
    l1 = fmaxf(l1, 0.f);
    float wl[12], wg[12];
    loadw12(w4, 198 + j*3, wl);
    loadw12(w4, 264 + j*3, wg);
    #pragma unroll
    for (int k = 0; k < 11; k++) acc[k] += l1*wl[k] + gg*wg[k];
  }
  if (!live) return;
  const float* av = wEl + 1320;
  float mean = 0.f;
  #pragma unroll
  for (int k = 0; k < 11; k++) { acc[k] = fmaxf(acc[k], 0.f); mean += acc[k]; }
  mean *= (1.f / 11.f);
  unsigned p[6];
  #pragma unroll
  for (int q = 0; q < 5; q++)
    p[q] = (unsigned)tobu(acc[2*q]) | ((unsigned)tobu(acc[2*q+1]) << 16);
  p[5] = (unsigned)tobu(acc[10]);
  uint2* er = eab + (size_t)e * 3;
  er[0] = make_uint2(p[0], p[1]);
  er[1] = make_uint2(p[2], p[3]);
  er[2] = make_uint2(p[4], p[5]);
  int s = srcA[e];
  const uint2* hb = (const uint2*)(hpb + (size_t)s * 32);
  float dot = 0.f;
  #pragma unroll
  for (int q = 0; q < 8; q++) {
    uint2 hv = hb[q];
    dot += b2f((unsigned short)hv.x) * av[q*4+0] + b2f((unsigned short)(hv.x >> 16)) * av[q*4+1]
         + b2f((unsigned short)hv.y) * av[q*4+2] + b2f((unsigned short)(hv.y >> 16)) * av[q*4+3];
  }
  raw_out[e] = mean * dot;
}

// ---------------- per-node aggregation with online segment softmax ----------------
__device__ __forceinline__ void unpack_ev(uint2 q0, uint2 q1, uint2 q2, float* ev) {
  ev[0] = b2f((unsigned short)q0.x); ev[1] = b2f((unsigned short)(q0.x >> 16));
  ev[2] = b2f((unsigned short)q0.y); ev[3] = b2f((unsigned short)(q0.y >> 16));
  ev[4] = b2f((unsigned short)q1.x); ev[5] = b2f((unsigned short)(q1.x >> 16));
  ev[6] = b2f((unsigned short)q1.y); ev[7] = b2f((unsigned short)(q1.y >> 16));
  ev[8] = b2f((unsigned short)q2.x); ev[9] = b2f((unsigned short)(q2.x >> 16));
  ev[10] = b2f((unsigned short)q2.y);
}

__global__ __launch_bounds__(256) void node_kernel(const int* __restrict__ offs, const int* __restrict__ elist,
                                                   const int* __restrict__ srcA,
                                                   const uint2* __restrict__ eab, const float* __restrict__ raw,
                                                   const unsigned short* __restrict__ hpb,
                                                   bf16* __restrict__ Abuf, float* __restrict__ atts, int N) {
  int wid = threadIdx.x >> 6, lane = threadIdx.x & 63;
  int half = lane >> 5, d = lane & 31;
  int n = blockIdx.x * 4 + wid;
  if (n >= N_PAD) return;
  bool valid = (n < N);
  int beg = 0, deg = 0;
  if (valid) { beg = offs[n]; deg = offs[n + 1] - beg; }

  float agg[11], watt[11];
  #pragma unroll
  for (int k = 0; k < 11; k++) { agg[k] = 0.f; watt[k] = 0.f; }
  float m = -1e30f, denom = 0.f;

  int j = half;
  // 2-edge ILP: issue both dependent-load chains together
  for (; j + 2 < deg; j += 4) {
    int ia = elist[beg + j], ib = elist[beg + j + 2];
    int sa = srcA[ia], sb = srcA[ib];
    float xa = b2f(hpb[(size_t)sa * 32 + d]);
    float xb = b2f(hpb[(size_t)sb * 32 + d]);
    float ra = raw[ia], rb = raw[ib];
    uint2 a0 = eab[(size_t)ia * 3], a1 = eab[(size_t)ia * 3 + 1], a2 = eab[(size_t)ia * 3 + 2];
    uint2 b0 = eab[(size_t)ib * 3], b1 = eab[(size_t)ib * 3 + 1], b2q = eab[(size_t)ib * 3 + 2];
    float eva[11], evb[11];
    unpack_ev(a0, a1, a2, eva);
    unpack_ev(b0, b1, b2q, evb);
    if (ra > m) {
      float sc = __expf(m - ra);
      denom *= sc;
      #pragma unroll
      for (int k = 0; k < 11; k++) watt[k] *= sc;
      m = ra;
    }
    float pa = __expf(ra - m);
    denom += pa;
    #pragma unroll
    for (int k = 0; k < 11; k++) { float t = eva[k]; agg[k] += t * xa; watt[k] += (pa * t) * xa; }
    if (rb > m) {
      float sc = __expf(m - rb);
      denom *= sc;
      #pragma unroll
      for (int k = 0; k < 11; k++) watt[k] *= sc;
      m = rb;
    }
    float pb = __expf(rb - m);
    denom += pb;
    #pragma unroll
    for (int k = 0; k < 11; k++) { float t = evb[k]; agg[k] += t * xb; watt[k] += (pb * t) * xb; }
  }
  for (; j < deg; j += 2) {
    int eid = elist[beg + j];
    int s = srcA[eid];
    float xs = b2f(hpb[(size_t)s * 32 + d]);
    float r = raw[eid];
    uint2 q0 = eab[(size_t)eid * 3], q1 = eab[(size_t)eid * 3 + 1], q2 = eab[(size_t)eid * 3 + 2];
    float ev[11];
    unpack_ev(q0, q1, q2, ev);
    if (r > m) {
      float sc = __expf(m - r);
      denom *= sc;
      #pragma unroll
      for (int k = 0; k < 11; k++) watt[k] *= sc;
      m = r;
    }
    float p = __expf(r - m);
    denom += p;
    #pragma unroll
    for (int k = 0; k < 11; k++) { float t = ev[k]; agg[k] += t * xs; watt[k] += (p * t) * xs; }
  }

  // merge the two halves
  float m_o = __shfl_xor(m, 32);
  float M = fmaxf(m, m_o);
  float ss = __expf(m - M);
  float so = __expf(m_o - M);
  float den_o = __shfl_xor(denom, 32);
  float denT = denom * ss + den_o * so;
  float inv = 1.f / (denT + 1e-16f);
  float comb[11];
  #pragma unroll
  for (int k = 0; k < 11; k++) {
    float ao = __shfl_xor(agg[k], 32);
    float wo = __shfl_xor(watt[k], 32);
    comb[k] = (agg[k] + ao) + (watt[k] * ss + wo * so) * inv;
  }

  if (half == 0) {
    bf16* arow = Abuf + (size_t)n * 352 + d * 11;
    #pragma unroll
    for (int k = 0; k < 11; k++) arow[k] = tob(comb[k]);
  }

  for (int jj = lane; jj < deg; jj += 64) {
    int eid = elist[beg + jj];
    atts[eid] = __expf(raw[eid] - M) * inv;
  }
}

// ---------------- fused conv GEMM + epilogue ----------------
__global__ __launch_bounds__(256) void convfused_kernel(const short* __restrict__ A, const short* __restrict__ Wt,
                                                        const short* __restrict__ owB,
                                                        const float* __restrict__ hp, float* __restrict__ h,
                                                        const float* __restrict__ convb,
                                                        const float* __restrict__ s1w, const float* __restrict__ s1b,
                                                        const float* __restrict__ s2w, const float* __restrict__ s2b,
                                                        const float* __restrict__ outb, int N) {
  __shared__ short slo[64][40];
  __shared__ float sdelta[64][36];
  __shared__ float sskipw[128];
  __shared__ float sskipb[4];
  __shared__ float scb[32];
  __shared__ float sob[32];
  int tid = threadIdx.x;
  if (tid < 64) sskipw[tid] = s1w[tid];
  if (tid >= 64 && tid < 128) sskipw[tid] = s2w[tid - 64];
  if (tid >= 128 && tid < 160) sob[tid - 128] = outb[tid - 128];
  if (tid >= 160 && tid < 192) scb[tid - 160] = (tid - 160 < 30) ? convb[tid - 160] : 0.f;
  if (tid >= 192 && tid < 196) sskipb[tid - 192] = (tid < 194) ? s1b[tid - 192] : s2b[tid - 194];
  __syncthreads();

  int wave = tid >> 6, lane = tid & 63;
  int r16 = lane & 15, kq = lane >> 4;
  int mbase = blockIdx.x * 64 + wave * 16;

  const short* arow = A + (size_t)(mbase + r16) * 352 + kq * 8;
  const short* b0p = Wt + (size_t)r16 * 352 + kq * 8;
  const short* b1p = b0p + 16 * 352;
  f32x4v acc0 = {0.f, 0.f, 0.f, 0.f}, acc1 = {0.f, 0.f, 0.f, 0.f};
  #pragma unroll
  for (int ks = 0; ks < 11; ks++) {
    bf16x8 af = *(const bf16x8*)(arow + ks * 32);
    bf16x8 b0 = *(const bf16x8*)(b0p + ks * 32);
    bf16x8 b1 = *(const bf16x8*)(b1p + ks * 32);
    acc0 = __builtin_amdgcn_mfma_f32_16x16x32_bf16(af, b0, acc0, 0, 0, 0);
    acc1 = __builtin_amdgcn_mfma_f32_16x16x32_bf16(af, b1, acc1, 0, 0, 0);
  }
  #pragma unroll
  for (int r = 0; r < 4; r++) {
    int row = wave * 16 + kq * 4 + r;
    slo[row][r16] = (short)tobu(fmaxf(acc0[r] + scb[r16], 0.f));
    if (r16 < 14) slo[row][16 + r16] = (short)tobu(fmaxf(acc1[r] + scb[16 + r16], 0.f));
  }
  __syncthreads();

  if (tid < 128) {
    int row = tid >> 1, jx = tid & 1;
    int grow = blockIdx.x * 64 + row;
    float a1 = sskipb[jx], a2 = sskipb[2 + jx];
    if (grow < N) {
      const float* hr = hp + (size_t)grow * 32;
      #pragma unroll
      for (int dd = 0; dd < 32; dd++) {
        float hv = hr[dd];
        a1 += hv * sskipw[dd*2 + jx];
        a2 += hv * sskipw[64 + dd*2 + jx];
      }
    }
    slo[row][30 + jx] = (short)tobu(tanh_fast(a1) * tanh_fast(a2));
  }
  __syncthreads();

  bf16x8 a2f = *(const bf16x8*)&slo[wave * 16 + r16][kq * 8];
  bf16x8 bo0 = *(const bf16x8*)(owB + lane * 8);
  bf16x8 bo1 = *(const bf16x8*)(owB + 512 + lane * 8);
  f32x4v d0 = {0.f, 0.f, 0.f, 0.f}, d1 = {0.f, 0.f, 0.f, 0.f};
  d0 = __builtin_amdgcn_mfma_f32_16x16x32_bf16(a2f, bo0, d0, 0, 0, 0);
  d1 = __builtin_amdgcn_mfma_f32_16x16x32_bf16(a2f, bo1, d1, 0, 0, 0);
  #pragma unroll
  for (int r = 0; r < 4; r++) {
    int row = wave * 16 + kq * 4 + r;
    sdelta[row][r16] = d0[r] + sob[r16];
    sdelta[row][16 + r16] = d1[r] + sob[16 + r16];
  }
  __syncthreads();

  {
    int row = tid >> 2, col0 = (tid & 3) * 8;
    int grow = blockIdx.x * 64 + row;
    if (grow < N) {
      float* hr = h + (size_t)grow * 32 + col0;
      float4 ha = *(float4*)hr;
      float4 hb = *(float4*)(hr + 4);
      float4 da = *(float4*)&sdelta[row][col0];
      float4 db = *(float4*)&sdelta[row][col0 + 4];
      ha.x += da.x; ha.y += da.y; ha.z += da.z; ha.w += da.w;
      hb.x += db.x; hb.y += db.y; hb.z += db.z; hb.w += db.w;
      *(float4*)hr = ha;
      *(float4*)(hr + 4) = hb;
    }
  }
}

// ---------------- graph bounds + fused pool / outh / final head ----------------
__global__ void bounds_kernel(const int* __restrict__ batch, int* __restrict__ gb) {
  int g = threadIdx.x;
  if (g > N_GR) return;
  if (g == N_GR) { gb[g] = N_NODES; return; }
  int lo = 0, hi = N_NODES;
  while (lo < hi) { int mid = (lo + hi) >> 1; if (batch[mid] < g) lo = mid + 1; else hi = mid; }
  gb[g] = lo;
}

__global__ __launch_bounds__(256) void pool2_kernel(const float* __restrict__ h, const int* __restrict__ gb,
                                                    const float* __restrict__ fw, const float* __restrict__ fb,
                                                    float* __restrict__ out0, float* __restrict__ outh) {
  __shared__ float part[8][32];
  __shared__ float pooled[32];
  int g = blockIdx.x;
  int s = gb[g], e = gb[g + 1];
  int grp = threadIdx.x >> 5, d = threadIdx.x & 31;
  float acc = 0.f;
  for (int n = s + grp; n < e; n += 8) {
    float v = h[(size_t)n * 32 + d];
    outh[(size_t)n * 32 + d] = v;
    acc += v;
  }
  part[grp][d] = acc;
  __syncthreads();
  if (threadIdx.x < 32) {
    float sum = 0.f;
    #pragma unroll
    for (int i = 0; i < 8; i++) sum += part[i][d];
    pooled[d] = sum / fmaxf((float)(e - s), 1.f);
  }
  __syncthreads();
  if (threadIdx.x < 32) {
    int jx = threadIdx.x;
    float o = fb[jx];
    #pragma unroll
    for (int dd = 0; dd < 32; dd++) o += pooled[dd] * fw[dd*32 + jx];
    out0[g * 32 + jx] = o;
  }
}

extern "C" void kernel_launch(void* const* d_in, const int* in_sizes, int n_in,
                              void* d_out, int out_size, void* d_ws, size_t ws_size,
                              hipStream_t stream) {
  (void)in_sizes; (void)n_in; (void)out_size; (void)ws_size;
  const float* x      = (const float*)d_in[0];
  const float* eattr  = (const float*)d_in[1];
  const int* eidx     = (const int*)d_in[2];
  const int* batch    = (const int*)d_in[3];
  const float* emb_w  = (const float*)d_in[4];
  const float* emb_b  = (const float*)d_in[5];
  const float* init_w = (const float*)d_in[6];
  const float* e1w    = (const float*)d_in[7];
  const float* e2w    = (const float*)d_in[8];
  const float* e3w    = (const float*)d_in[9];
  const float* e4w    = (const float*)d_in[10];
  const float* convw  = (const float*)d_in[11];
  const float* convb  = (const float*)d_in[12];
  const float* attv   = (const float*)d_in[13];
  const float* s1w    = (const float*)d_in[14];
  const float* s1b    = (const float*)d_in[15];
  const float* s2w    = (const float*)d_in[16];
  const float* s2b    = (const float*)d_in[17];
  const float* outw   = (const float*)d_in[18];
  const float* outb   = (const float*)d_in[19];
  const float* finw   = (const float*)d_in[20];
  const float* finb   = (const float*)d_in[21];

  char* ws = (char*)d_ws;
  size_t off = 0;
  auto take = [&](size_t bytes) -> char* {
    char* p = ws + off;
    off += (bytes + 255) & ~(size_t)255;
    return p;
  };
  float* h    = (float*)take((size_t)N_NODES * 32 * 4);
  float* hp   = (float*)take((size_t)N_NODES * 32 * 4);
  unsigned short* hpb = (unsigned short*)take((size_t)N_NODES * 32 * 2);
  uint2* eab  = (uint2*)take((size_t)N_EDGES * 24);
  float* raw  = (float*)take((size_t)N_EDGES * 4);
  bf16*  Abuf = (bf16*)take((size_t)N_PAD * 352 * 2);
  int*   deg  = (int*)take((size_t)N_NODES * 4);
  int*   offs = (int*)take((size_t)(N_NODES + 1) * 4);
  int*   cur  = (int*)take((size_t)N_NODES * 4);
  int*   elist= (int*)take((size_t)N_EDGES * 4);
  int*   gb   = (int*)take((size_t)(N_GR + 1) * 4);
  float* wE   = (float*)take((size_t)2 * 1352 * 4);
  bf16*  Wt   = (bf16*)take((size_t)2 * 32 * 352 * 2);
  bf16*  owB  = (bf16*)take((size_t)2048 * 2);

  float* out0 = (float*)d_out;
  float* outh = out0 + N_GR * 32;
  float* outa = outh + (size_t)N_NODES * 32;

  const int* srcA = eidx;
  const int* dstA = eidx + N_EDGES;

  hipMemsetAsync(deg, 0, (size_t)N_NODES * 4, stream);

  prep_kernel<<<107, 256, 0, stream>>>(e1w, e2w, e3w, e4w, attv, convw, outw, wE, Wt, owB);
  hist_kernel<<<(N_EDGES + 255) / 256, 256, 0, stream>>>(dstA, deg, N_EDGES);
  scan_kernel<<<1, 1024, 0, stream>>>(deg, offs, cur, N_NODES);
  fill_kernel<<<(N_EDGES + 255) / 256, 256, 0, stream>>>(dstA, cur, elist, N_EDGES);
  emb_kernel<<<(N_NODES * 32 + 255) / 256, 256, 0, stream>>>(x, emb_w, emb_b, h, N_NODES);
  bounds_kernel<<<1, 128, 0, stream>>>(batch, gb);

  for (int l = 0; l < 2; l++) {
    hproj_kernel<<<(N_NODES * 32 + 255) / 256, 256, 0, stream>>>(h, init_w + l * 1024, hp, hpb, N_NODES);
    edge_kernel<<<(N_EDGES + 255) / 256, 256, 0, stream>>>(
        eattr, srcA, hpb, wE + l * 1352, eab, raw, N_EDGES);
    node_kernel<<<N_PAD / 4, 256, 0, stream>>>(offs, elist, srcA, eab, raw, hpb,
                                               Abuf, outa + (size_t)l * N_EDGES, N_NODES);
    convfused_kernel<<<N_PAD / 64, 256, 0, stream>>>(
        (const short*)Abuf, (const short*)Wt + (size_t)l * 32 * 352, (const short*)owB + (size_t)l * 1024,
        hp, h, convb + l * 30, s1w + l * 64, s1b + l * 2, s2w + l * 64, s2b + l * 2,
        outb + l * 32, N_NODES);
  }

  pool2_kernel<<<N_GR, 256, 0, stream>>>(h, gb, finw, finb, out0, outh);
}

// Round 5
// 257.849 us; speedup vs baseline: 1.7164x; 1.0753x over previous
//
#include <hip/hip_runtime.h>
#include <hip/hip_bf16.h>

typedef __hip_bfloat16 bf16;
using f32x4v = __attribute__((ext_vector_type(4))) float;
using bf16x8 = __attribute__((ext_vector_type(8))) short;

#define N_NODES 25000
#define N_PAD   25024   // multiple of 64 for fused conv kernel
#define N_EDGES 400000
#define N_GR    100

__device__ __forceinline__ bf16 tob(float v) { return __float2bfloat16(v); }
__device__ __forceinline__ unsigned short tobu(float v) {
  union { bf16 b; unsigned short u; } c; c.b = __float2bfloat16(v); return c.u;
}
__device__ __forceinline__ float b2f(unsigned short u) { return __uint_as_float(((unsigned)u) << 16); }
__device__ __forceinline__ float tanh_fast(float x) {
  float cx = fminf(fmaxf(x, -10.f), 10.f);
  float e = __expf(2.f * cx);
  return (e - 1.f) / (e + 1.f);
}

// ---------------- CSR build ----------------
__global__ __launch_bounds__(256) void hist_kernel(const int* __restrict__ dst, int* __restrict__ deg, int E) {
  int e = blockIdx.x * blockDim.x + threadIdx.x;
  if (e < E) atomicAdd(&deg[dst[e]], 1);
}

__global__ __launch_bounds__(1024) void scan_kernel(const int* __restrict__ deg, int* __restrict__ offs,
                                                    int* __restrict__ cur, int n) {
  __shared__ int wsum[16];
  __shared__ int wpre[16];
  int t = threadIdx.x, lane = t & 63, w = t >> 6;
  int carry = 0;
  for (int base = 0; base < n; base += 1024) {
    int v = (base + t < n) ? deg[base + t] : 0;
    int x = v;
    #pragma unroll
    for (int s = 1; s < 64; s <<= 1) { int y = __shfl_up(x, s); if (lane >= s) x += y; }
    if (lane == 63) wsum[w] = x;
    __syncthreads();
    if (w == 0 && lane < 16) {
      int ws_ = wsum[lane];
      int xs = ws_;
      #pragma unroll
      for (int s = 1; s < 16; s <<= 1) { int y = __shfl_up(xs, s); if (lane >= s) xs += y; }
      wpre[lane] = xs - ws_;
    }
    __syncthreads();
    int excl = carry + wpre[w] + x - v;
    if (base + t < n) { offs[base + t] = excl; cur[base + t] = excl; }
    carry += wpre[15] + wsum[15];
    __syncthreads();
  }
  if (t == 0) offs[n] = carry;
}

__global__ __launch_bounds__(256) void fill_kernel(const int* __restrict__ dst, int* __restrict__ cur,
                                                   int* __restrict__ elist, int* __restrict__ epos, int E) {
  int e = blockIdx.x * blockDim.x + threadIdx.x;
  if (e < E) { int p = atomicAdd(&cur[dst[e]], 1); elist[p] = e; epos[e] = p; }
}

// ---------------- weight prep ----------------
// wE per layer (1352 f32): [e1t 22x12][e2t 22x12][e3t 22x12][e4L 22x12][e4G 22x12][attv 32]
// Wt  per layer (32x352 bf16): Wt[o][d*11+kk] = conv_w[kk][d][o]  (o>=30 zero)
// owB per layer (2x64x8 bf16): owB[hf][lane][j] = outw[k*32 + hf*16 + n], k=(lane>>4)*8+j, n=lane&15
__global__ __launch_bounds__(256) void prep_kernel(const float* __restrict__ e1, const float* __restrict__ e2,
                                                   const float* __restrict__ e3, const float* __restrict__ e4,
                                                   const float* __restrict__ attv, const float* __restrict__ convw,
                                                   const float* __restrict__ outw,
                                                   float* __restrict__ wE, bf16* __restrict__ Wt,
                                                   bf16* __restrict__ owB) {
  int i = blockIdx.x * blockDim.x + threadIdx.x;
  if (i < 2 * 1352) {
    int l = i / 1352, r = i % 1352;
    float v = 0.f;
    if (r < 264)       { int q = r;        int j = q / 12, k = q % 12; if (k < 11) v = e1[l*242 + k*22 + j]; }
    else if (r < 528)  { int q = r - 264;  int j = q / 12, k = q % 12; if (k < 11) v = e2[l*242 + k*22 + j]; }
    else if (r < 792)  { int q = r - 528;  int j = q / 12, k = q % 12; if (k < 11) v = e3[l*242 + k*22 + j]; }
    else if (r < 1056) { int q = r - 792;  int j = q / 12, k = q % 12; if (k < 11) v = e4[l*484 + j*11 + k]; }
    else if (r < 1320) { int q = r - 1056; int j = q / 12, k = q % 12; if (k < 11) v = e4[l*484 + (22 + j)*11 + k]; }
    else               { int d = r - 1320; v = attv[l*32 + d]; }
    wE[i] = v;
  }
  int t = i - 2 * 1352;
  if (t >= 0 && t < 2 * 32 * 352) {
    int l = t / (32 * 352), q = t % (32 * 352);
    int o = q / 352, dk = q % 352;
    int d = dk / 11, kk = dk % 11;
    float v = 0.f;
    if (o < 30) v = convw[l*10560 + (kk*32 + d)*30 + o];
    Wt[t] = tob(v);
  }
  int u = i - 2 * 1352 - 2 * 32 * 352;
  if (u >= 0 && u < 2048) {
    int l = u >> 10, rem = u & 1023;
    int hf = rem >> 9, rem2 = rem & 511;
    int lane = rem2 >> 3, j = rem2 & 7;
    int k = (lane >> 4) * 8 + j, n = lane & 15;
    owB[u] = tob(outw[l*1024 + k*32 + hf*16 + n]);
  }
}

// ---------------- fused embedding + h_proj(layer 0) ----------------
__global__ __launch_bounds__(256) void emb_hproj_kernel(const float* __restrict__ x, const float* __restrict__ w,
                                                        const float* __restrict__ b, const float* __restrict__ w1,
                                                        float* __restrict__ h, float* __restrict__ hp,
                                                        unsigned short* __restrict__ hpb, int N) {
  __shared__ float semb[16 * 32];
  __shared__ float sw1[32 * 32];
  __shared__ float sb[32];
  __shared__ float sx[8][16];
  __shared__ float sh[8][33];
  int tid = threadIdx.x;
  for (int i = tid; i < 16 * 32; i += 256) semb[i] = w[i];
  for (int i = tid; i < 32 * 32; i += 256) sw1[i] = w1[i];
  if (tid < 32) sb[tid] = b[tid];
  int nb = blockIdx.x * 8;
  if (tid < 128) {
    int n = nb + (tid >> 4), k = tid & 15;
    sx[tid >> 4][k] = (n < N) ? x[(size_t)n * 16 + k] : 0.f;
  }
  __syncthreads();
  int grp = tid >> 5, d = tid & 31;
  int n = nb + grp;
  float acc = sb[d];
  #pragma unroll
  for (int k = 0; k < 16; k++) acc += sx[grp][k] * semb[k*32 + d];
  sh[grp][d] = acc;
  if (n < N) h[(size_t)n * 32 + d] = acc;
  __syncthreads();
  float hpv = 0.f;
  #pragma unroll
  for (int k = 0; k < 32; k++) hpv += sh[grp][k] * sw1[k*32 + d];
  if (n < N) {
    hp[(size_t)n * 32 + d] = hpv;
    hpb[(size_t)n * 32 + d] = tobu(hpv);
  }
}

// ---------------- edge MLP + raw attention -> CSR-ordered payload ----------------
// payload[p] (32B, two uint4): {ea[0..7]}, {ea[8..10], raw(f32), src(int)}
__device__ __forceinline__ void loadw12(const float4* base, int idx3, float* w) {
  float4 a = base[idx3], b = base[idx3 + 1], c = base[idx3 + 2];
  w[0]=a.x; w[1]=a.y; w[2]=a.z; w[3]=a.w;
  w[4]=b.x; w[5]=b.y; w[6]=b.z; w[7]=b.w;
  w[8]=c.x; w[9]=c.y; w[10]=c.z; w[11]=c.w;
}

__global__ __launch_bounds__(256) void edge_kernel(const float* __restrict__ eattr,
                                                   const int* __restrict__ srcA,
                                                   const int* __restrict__ epos,
                                                   const unsigned short* __restrict__ hpb,
                                                   const float* __restrict__ wEl,
                                                   uint4* __restrict__ pay, int E) {
  const float4* w4 = (const float4*)wEl;
  int e = blockIdx.x * blockDim.x + threadIdx.x;
  bool live = e < E;
  float a[11], acc[11];
  #pragma unroll
  for (int k = 0; k < 11; k++) {
    a[k] = live ? eattr[(size_t)e*11 + k] : 0.f;
    acc[k] = 0.f;
  }
  for (int j = 0; j < 22; j++) {
    float w[12];
    loadw12(w4, j*3, w);
    float l1 = 0.f;
    #pragma unroll
    for (int k = 0; k < 11; k++) l1 += a[k] * w[k];
    loadw12(w4, 66 + j*3, w);
    float l2 = 0.f;
    #pragma unroll
    for (int k = 0; k < 11; k++) l2 += a[k] * w[k];
    loadw12(w4, 132 + j*3, w);
    float l3 = 0.f;
    #pragma unroll
    for (int k = 0; k < 11; k++) l3 += a[k] * w[k];
    float gg = tanh_fast(l2) * tanh_fast(l3);
    l1 = fmaxf(l1, 0.f);
    float wl[12], wg[12];
    loadw12(w4, 198 + j*3, wl);
    loadw12(w4, 264 + j*3, wg);
    #pragma unroll
    for (int k = 0; k < 11; k++) acc[k] += l1*wl[k] + gg*wg[k];
  }
  if (!live) return;
  const float* av = wEl + 1320;
  float mean = 0.f;
  #pragma unroll
  for (int k = 0; k < 11; k++) { acc[k] = fmaxf(acc[k], 0.f); mean += acc[k]; }
  mean *= (1.f / 11.f);
  int s = srcA[e];
  const uint2* hb = (const uint2*)(hpb + (size_t)s * 32);
  float dot = 0.f;
  #pragma unroll
  for (int q = 0; q < 8; q++) {
    uint2 hv = hb[q];
    dot += b2f((unsigned short)hv.x) * av[q*4+0] + b2f((unsigned short)(hv.x >> 16)) * av[q*4+1]
         + b2f((unsigned short)hv.y) * av[q*4+2] + b2f((unsigned short)(hv.y >> 16)) * av[q*4+3];
  }
  float raw = mean * dot;
  unsigned p[6];
  #pragma unroll
  for (int q = 0; q < 5; q++)
    p[q] = (unsigned)tobu(acc[2*q]) | ((unsigned)tobu(acc[2*q+1]) << 16);
  p[5] = (unsigned)tobu(acc[10]);
  int pp = epos[e];
  pay[(size_t)pp * 2]     = make_uint4(p[0], p[1], p[2], p[3]);
  pay[(size_t)pp * 2 + 1] = make_uint4(p[4], p[5], __float_as_uint(raw), (unsigned)s);
}

// ---------------- per-node aggregation with online segment softmax ----------------
__device__ __forceinline__ void unpack_pay(uint4 p0, uint4 p1, float* ev) {
  ev[0] = b2f((unsigned short)p0.x); ev[1] = b2f((unsigned short)(p0.x >> 16));
  ev[2] = b2f((unsigned short)p0.y); ev[3] = b2f((unsigned short)(p0.y >> 16));
  ev[4] = b2f((unsigned short)p0.z); ev[5] = b2f((unsigned short)(p0.z >> 16));
  ev[6] = b2f((unsigned short)p0.w); ev[7] = b2f((unsigned short)(p0.w >> 16));
  ev[8] = b2f((unsigned short)p1.x); ev[9] = b2f((unsigned short)(p1.x >> 16));
  ev[10] = b2f((unsigned short)p1.y);
}

__global__ __launch_bounds__(256) void node_kernel(const int* __restrict__ offs, const int* __restrict__ elist,
                                                   const uint4* __restrict__ pay,
                                                   const unsigned short* __restrict__ hpb,
                                                   bf16* __restrict__ Abuf, float* __restrict__ atts, int N) {
  int wid = threadIdx.x >> 6, lane = threadIdx.x & 63;
  int half = lane >> 5, d = lane & 31;
  int n = blockIdx.x * 4 + wid;
  if (n >= N_PAD) return;
  bool valid = (n < N);
  int beg = 0, deg = 0;
  if (valid) { beg = offs[n]; deg = offs[n + 1] - beg; }

  float agg[11], watt[11];
  #pragma unroll
  for (int k = 0; k < 11; k++) { agg[k] = 0.f; watt[k] = 0.f; }
  float m = -1e30f, denom = 0.f;

  int j = half;
  for (; j + 2 < deg; j += 4) {
    uint4 a0 = pay[(size_t)(beg + j) * 2],     a1 = pay[(size_t)(beg + j) * 2 + 1];
    uint4 b0 = pay[(size_t)(beg + j + 2) * 2], b1 = pay[(size_t)(beg + j + 2) * 2 + 1];
    float xa = b2f(hpb[(size_t)(int)a1.w * 32 + d]);
    float xb = b2f(hpb[(size_t)(int)b1.w * 32 + d]);
    float ra = __uint_as_float(a1.z), rb = __uint_as_float(b1.z);
    float eva[11], evb[11];
    unpack_pay(a0, a1, eva);
    unpack_pay(b0, b1, evb);
    if (ra > m) {
      float sc = __expf(m - ra);
      denom *= sc;
      #pragma unroll
      for (int k = 0; k < 11; k++) watt[k] *= sc;
      m = ra;
    }
    float pa = __expf(ra - m);
    denom += pa;
    #pragma unroll
    for (int k = 0; k < 11; k++) { float t = eva[k]; agg[k] += t * xa; watt[k] += (pa * t) * xa; }
    if (rb > m) {
      float sc = __expf(m - rb);
      denom *= sc;
      #pragma unroll
      for (int k = 0; k < 11; k++) watt[k] *= sc;
      m = rb;
    }
    float pb = __expf(rb - m);
    denom += pb;
    #pragma unroll
    for (int k = 0; k < 11; k++) { float t = evb[k]; agg[k] += t * xb; watt[k] += (pb * t) * xb; }
  }
  for (; j < deg; j += 2) {
    uint4 q0 = pay[(size_t)(beg + j) * 2], q1 = pay[(size_t)(beg + j) * 2 + 1];
    float xs = b2f(hpb[(size_t)(int)q1.w * 32 + d]);
    float r = __uint_as_float(q1.z);
    float ev[11];
    unpack_pay(q0, q1, ev);
    if (r > m) {
      float sc = __expf(m - r);
      denom *= sc;
      #pragma unroll
      for (int k = 0; k < 11; k++) watt[k] *= sc;
      m = r;
    }
    float p = __expf(r - m);
    denom += p;
    #pragma unroll
    for (int k = 0; k < 11; k++) { float t = ev[k]; agg[k] += t * xs; watt[k] += (p * t) * xs; }
  }

  // merge the two halves
  float m_o = __shfl_xor(m, 32);
  float M = fmaxf(m, m_o);
  float ss = __expf(m - M);
  float so = __expf(m_o - M);
  float den_o = __shfl_xor(denom, 32);
  float denT = denom * ss + den_o * so;
  float inv = 1.f / (denT + 1e-16f);
  float comb[11];
  #pragma unroll
  for (int k = 0; k < 11; k++) {
    float ao = __shfl_xor(agg[k], 32);
    float wo = __shfl_xor(watt[k], 32);
    comb[k] = (agg[k] + ao) + (watt[k] * ss + wo * so) * inv;
  }

  if (half == 0) {
    bf16* arow = Abuf + (size_t)n * 352 + d * 11;
    #pragma unroll
    for (int k = 0; k < 11; k++) arow[k] = tob(comb[k]);
  }

  for (int jj = lane; jj < deg; jj += 64) {
    float r = __uint_as_float(pay[(size_t)(beg + jj) * 2 + 1].z);
    atts[elist[beg + jj]] = __expf(r - M) * inv;
  }
}

// ---------------- fused conv GEMM + epilogue (+ optional next-layer h_proj) ----------------
__global__ __launch_bounds__(256) void convfused_kernel(const short* __restrict__ A, const short* __restrict__ Wt,
                                                        const short* __restrict__ owB,
                                                        const float* __restrict__ hp, float* __restrict__ h,
                                                        const float* __restrict__ convb,
                                                        const float* __restrict__ s1w, const float* __restrict__ s1b,
                                                        const float* __restrict__ s2w, const float* __restrict__ s2b,
                                                        const float* __restrict__ outb,
                                                        const float* __restrict__ initw_next,
                                                        float* __restrict__ hp_out, unsigned short* __restrict__ hpb_out,
                                                        int N) {
  __shared__ short slo[64][40];
  __shared__ float sdelta[64][36];
  __shared__ float sskipw[128];
  __shared__ float sskipb[4];
  __shared__ float scb[32];
  __shared__ float sob[32];
  __shared__ float sw1[1024];
  int tid = threadIdx.x;
  if (tid < 64) sskipw[tid] = s1w[tid];
  if (tid >= 64 && tid < 128) sskipw[tid] = s2w[tid - 64];
  if (tid >= 128 && tid < 160) sob[tid - 128] = outb[tid - 128];
  if (tid >= 160 && tid < 192) scb[tid - 160] = (tid - 160 < 30) ? convb[tid - 160] : 0.f;
  if (tid >= 192 && tid < 196) sskipb[tid - 192] = (tid < 194) ? s1b[tid - 192] : s2b[tid - 194];
  if (initw_next) {
    for (int i = tid; i < 1024; i += 256) sw1[i] = initw_next[i];
  }
  __syncthreads();

  int wave = tid >> 6, lane = tid & 63;
  int r16 = lane & 15, kq = lane >> 4;
  int mbase = blockIdx.x * 64 + wave * 16;

  const short* arow = A + (size_t)(mbase + r16) * 352 + kq * 8;
  const short* b0p = Wt + (size_t)r16 * 352 + kq * 8;
  const short* b1p = b0p + 16 * 352;
  f32x4v acc0 = {0.f, 0.f, 0.f, 0.f}, acc1 = {0.f, 0.f, 0.f, 0.f};
  #pragma unroll
  for (int ks = 0; ks < 11; ks++) {
    bf16x8 af = *(const bf16x8*)(arow + ks * 32);
    bf16x8 b0 = *(const bf16x8*)(b0p + ks * 32);
    bf16x8 b1 = *(const bf16x8*)(b1p + ks * 32);
    acc0 = __builtin_amdgcn_mfma_f32_16x16x32_bf16(af, b0, acc0, 0, 0, 0);
    acc1 = __builtin_amdgcn_mfma_f32_16x16x32_bf16(af, b1, acc1, 0, 0, 0);
  }
  #pragma unroll
  for (int r = 0; r < 4; r++) {
    int row = wave * 16 + kq * 4 + r;
    slo[row][r16] = (short)tobu(fmaxf(acc0[r] + scb[r16], 0.f));
    if (r16 < 14) slo[row][16 + r16] = (short)tobu(fmaxf(acc1[r] + scb[16 + r16], 0.f));
  }
  __syncthreads();

  if (tid < 128) {
    int row = tid >> 1, jx = tid & 1;
    int grow = blockIdx.x * 64 + row;
    float a1 = sskipb[jx], a2 = sskipb[2 + jx];
    if (grow < N) {
      const float* hr = hp + (size_t)grow * 32;
      #pragma unroll
      for (int dd = 0; dd < 32; dd++) {
        float hv = hr[dd];
        a1 += hv * sskipw[dd*2 + jx];
        a2 += hv * sskipw[64 + dd*2 + jx];
      }
    }
    slo[row][30 + jx] = (short)tobu(tanh_fast(a1) * tanh_fast(a2));
  }
  __syncthreads();

  bf16x8 a2f = *(const bf16x8*)&slo[wave * 16 + r16][kq * 8];
  bf16x8 bo0 = *(const bf16x8*)(owB + lane * 8);
  bf16x8 bo1 = *(const bf16x8*)(owB + 512 + lane * 8);
  f32x4v d0 = {0.f, 0.f, 0.f, 0.f}, d1 = {0.f, 0.f, 0.f, 0.f};
  d0 = __builtin_amdgcn_mfma_f32_16x16x32_bf16(a2f, bo0, d0, 0, 0, 0);
  d1 = __builtin_amdgcn_mfma_f32_16x16x32_bf16(a2f, bo1, d1, 0, 0, 0);
  #pragma unroll
  for (int r = 0; r < 4; r++) {
    int row = wave * 16 + kq * 4 + r;
    sdelta[row][r16] = d0[r] + sob[r16];
    sdelta[row][16 + r16] = d1[r] + sob[16 + r16];
  }
  __syncthreads();

  int row = tid >> 2, col0 = (tid & 3) * 8;
  int grow = blockIdx.x * 64 + row;
  if (grow < N) {
    float* hr = h + (size_t)grow * 32 + col0;
    float4 ha = *(float4*)hr;
    float4 hb = *(float4*)(hr + 4);
    float4 da = *(float4*)&sdelta[row][col0];
    float4 db = *(float4*)&sdelta[row][col0 + 4];
    ha.x += da.x; ha.y += da.y; ha.z += da.z; ha.w += da.w;
    hb.x += db.x; hb.y += db.y; hb.z += db.z; hb.w += db.w;
    *(float4*)hr = ha;
    *(float4*)(hr + 4) = hb;
    // stash h_new into sdelta for the fused next-layer h_proj
    *(float4*)&sdelta[row][col0] = ha;
    *(float4*)&sdelta[row][col0 + 4] = hb;
  }
  if (initw_next) {
    __syncthreads();
    if (grow < N) {
      float o[8];
      #pragma unroll
      for (int c = 0; c < 8; c++) o[c] = 0.f;
      #pragma unroll
      for (int k = 0; k < 32; k++) {
        float hv = sdelta[row][k];
        #pragma unroll
        for (int c = 0; c < 8; c++) o[c] += hv * sw1[k*32 + col0 + c];
      }
      float* hpo = hp_out + (size_t)grow * 32 + col0;
      unsigned short* hbo = hpb_out + (size_t)grow * 32 + col0;
      #pragma unroll
      for (int c = 0; c < 8; c++) { hpo[c] = o[c]; hbo[c] = tobu(o[c]); }
    }
  }
}

// ---------------- graph bounds + fused pool / outh / final head ----------------
__global__ void bounds_kernel(const int* __restrict__ batch, int* __restrict__ gb) {
  int g = threadIdx.x;
  if (g > N_GR) return;
  if (g == N_GR) { gb[g] = N_NODES; return; }
  int lo = 0, hi = N_NODES;
  while (lo < hi) { int mid = (lo + hi) >> 1; if (batch[mid] < g) lo = mid + 1; else hi = mid; }
  gb[g] = lo;
}

__global__ __launch_bounds__(256) void pool2_kernel(const float* __restrict__ h, const int* __restrict__ gb,
                                                    const float* __restrict__ fw, const float* __restrict__ fb,
                                                    float* __restrict__ out0, float* __restrict__ outh) {
  __shared__ float part[8][32];
  __shared__ float pooled[32];
  int g = blockIdx.x;
  int s = gb[g], e = gb[g + 1];
  int grp = threadIdx.x >> 5, d = threadIdx.x & 31;
  float acc = 0.f;
  for (int n = s + grp; n < e; n += 8) {
    float v = h[(size_t)n * 32 + d];
    outh[(size_t)n * 32 + d] = v;
    acc += v;
  }
  part[grp][d] = acc;
  __syncthreads();
  if (threadIdx.x < 32) {
    float sum = 0.f;
    #pragma unroll
    for (int i = 0; i < 8; i++) sum += part[i][d];
    pooled[d] = sum / fmaxf((float)(e - s), 1.f);
  }
  __syncthreads();
  if (threadIdx.x < 32) {
    int jx = threadIdx.x;
    float o = fb[jx];
    #pragma unroll
    for (int dd = 0; dd < 32; dd++) o += pooled[dd] * fw[dd*32 + jx];
    out0[g * 32 + jx] = o;
  }
}

extern "C" void kernel_launch(void* const* d_in, const int* in_sizes, int n_in,
                              void* d_out, int out_size, void* d_ws, size_t ws_size,
                              hipStream_t stream) {
  (void)in_sizes; (void)n_in; (void)out_size; (void)ws_size;
  const float* x      = (const float*)d_in[0];
  const float* eattr  = (const float*)d_in[1];
  const int* eidx     = (const int*)d_in[2];
  const int* batch    = (const int*)d_in[3];
  const float* emb_w  = (const float*)d_in[4];
  const float* emb_b  = (const float*)d_in[5];
  const float* init_w = (const float*)d_in[6];
  const float* e1w    = (const float*)d_in[7];
  const float* e2w    = (const float*)d_in[8];
  const float* e3w    = (const float*)d_in[9];
  const float* e4w    = (const float*)d_in[10];
  const float* convw  = (const float*)d_in[11];
  const float* convb  = (const float*)d_in[12];
  const float* attv   = (const float*)d_in[13];
  const float* s1w    = (const float*)d_in[14];
  const float* s1b    = (const float*)d_in[15];
  const float* s2w    = (const float*)d_in[16];
  const float* s2b    = (const float*)d_in[17];
  const float* outw   = (const float*)d_in[18];
  const float* outb   = (const float*)d_in[19];
  const float* finw   = (const float*)d_in[20];
  const float* finb   = (const float*)d_in[21];

  char* ws = (char*)d_ws;
  size_t off = 0;
  auto take = [&](size_t bytes) -> char* {
    char* p = ws + off;
    off += (bytes + 255) & ~(size_t)255;
    return p;
  };
  float* h    = (float*)take((size_t)N_NODES * 32 * 4);
  float* hp   = (float*)take((size_t)N_NODES * 32 * 4);
  unsigned short* hpb = (unsigned short*)take((size_t)N_NODES * 32 * 2);
  uint4* pay  = (uint4*)take((size_t)N_EDGES * 32);
  bf16*  Abuf = (bf16*)take((size_t)N_PAD * 352 * 2);
  int*   deg  = (int*)take((size_t)N_NODES * 4);
  int*   offs = (int*)take((size_t)(N_NODES + 1) * 4);
  int*   cur  = (int*)take((size_t)N_NODES * 4);
  int*   elist= (int*)take((size_t)N_EDGES * 4);
  int*   epos = (int*)take((size_t)N_EDGES * 4);
  int*   gb   = (int*)take((size_t)(N_GR + 1) * 4);
  float* wE   = (float*)take((size_t)2 * 1352 * 4);
  bf16*  Wt   = (bf16*)take((size_t)2 * 32 * 352 * 2);
  bf16*  owB  = (bf16*)take((size_t)2048 * 2);

  float* out0 = (float*)d_out;
  float* outh = out0 + N_GR * 32;
  float* outa = outh + (size_t)N_NODES * 32;

  const int* srcA = eidx;
  const int* dstA = eidx + N_EDGES;

  hipMemsetAsync(deg, 0, (size_t)N_NODES * 4, stream);

  prep_kernel<<<107, 256, 0, stream>>>(e1w, e2w, e3w, e4w, attv, convw, outw, wE, Wt, owB);
  hist_kernel<<<(N_EDGES + 255) / 256, 256, 0, stream>>>(dstA, deg, N_EDGES);
  scan_kernel<<<1, 1024, 0, stream>>>(deg, offs, cur, N_NODES);
  fill_kernel<<<(N_EDGES + 255) / 256, 256, 0, stream>>>(dstA, cur, elist, epos, N_EDGES);
  emb_hproj_kernel<<<(N_NODES + 7) / 8, 256, 0, stream>>>(x, emb_w, emb_b, init_w, h, hp, hpb, N_NODES);
  bounds_kernel<<<1, 128, 0, stream>>>(batch, gb);

  for (int l = 0; l < 2; l++) {
    edge_kernel<<<(N_EDGES + 255) / 256, 256, 0, stream>>>(
        eattr, srcA, epos, hpb, wE + l * 1352, pay, N_EDGES);
    node_kernel<<<N_PAD / 4, 256, 0, stream>>>(offs, elist, pay, hpb,
                                               Abuf, outa + (size_t)l * N_EDGES, N_NODES);
    convfused_kernel<<<N_PAD / 64, 256, 0, stream>>>(
        (const short*)Abuf, (const short*)Wt + (size_t)l * 32 * 352, (const short*)owB + (size_t)l * 1024,
        hp, h, convb + l * 30, s1w + l * 64, s1b + l * 2, s2w + l * 64, s2b + l * 2,
        outb + l * 32,
        (l == 0) ? (init_w + 1024) : nullptr, hp, hpb, N_NODES);
  }

  pool2_kernel<<<N_GR, 256, 0, stream>>>(h, gb, finw, finb, out0, outh);
}

// Round 6
// 246.537 us; speedup vs baseline: 1.7951x; 1.0459x over previous
//
#include <hip/hip_runtime.h>
#include <hip/hip_bf16.h>

typedef __hip_bfloat16 bf16;
using f32x4v = __attribute__((ext_vector_type(4))) float;
using bf16x8 = __attribute__((ext_vector_type(8))) short;

#define N_NODES 25000
#define N_PAD   25024   // multiple of 64 for fused conv kernel
#define N_EDGES 400000
#define N_GR    100

__device__ __forceinline__ bf16 tob(float v) { return __float2bfloat16(v); }
__device__ __forceinline__ unsigned short tobu(float v) {
  union { bf16 b; unsigned short u; } c; c.b = __float2bfloat16(v); return c.u;
}
__device__ __forceinline__ float b2f(unsigned short u) { return __uint_as_float(((unsigned)u) << 16); }
// clamp-free tanh: 1 - 2/(e^{2x}+1); inf-safe (e=inf -> 1, e=0 -> -1)
__device__ __forceinline__ float tanh_fast(float x) {
  float e = __expf(2.f * x);
  return 1.f - 2.f * __builtin_amdgcn_rcpf(e + 1.f);
}

// ---------------- CSR build ----------------
__global__ __launch_bounds__(256) void hist_kernel(const int* __restrict__ dst, int* __restrict__ deg, int E) {
  int e = blockIdx.x * blockDim.x + threadIdx.x;
  if (e < E) atomicAdd(&deg[dst[e]], 1);
}

__global__ __launch_bounds__(1024) void scan_kernel(const int* __restrict__ deg, int* __restrict__ offs,
                                                    int* __restrict__ cur, int n) {
  __shared__ int wsum[16];
  __shared__ int wpre[16];
  int t = threadIdx.x, lane = t & 63, w = t >> 6;
  int carry = 0;
  for (int base = 0; base < n; base += 1024) {
    int v = (base + t < n) ? deg[base + t] : 0;
    int x = v;
    #pragma unroll
    for (int s = 1; s < 64; s <<= 1) { int y = __shfl_up(x, s); if (lane >= s) x += y; }
    if (lane == 63) wsum[w] = x;
    __syncthreads();
    if (w == 0 && lane < 16) {
      int ws_ = wsum[lane];
      int xs = ws_;
      #pragma unroll
      for (int s = 1; s < 16; s <<= 1) { int y = __shfl_up(xs, s); if (lane >= s) xs += y; }
      wpre[lane] = xs - ws_;
    }
    __syncthreads();
    int excl = carry + wpre[w] + x - v;
    if (base + t < n) { offs[base + t] = excl; cur[base + t] = excl; }
    carry += wpre[15] + wsum[15];
    __syncthreads();
  }
  if (t == 0) offs[n] = carry;
}

__global__ __launch_bounds__(256) void fill_kernel(const int* __restrict__ dst, int* __restrict__ cur,
                                                   int* __restrict__ elist, int* __restrict__ epos, int E) {
  int e = blockIdx.x * blockDim.x + threadIdx.x;
  if (e < E) { int p = atomicAdd(&cur[dst[e]], 1); elist[p] = e; epos[e] = p; }
}

// ---------------- weight prep (+ graph bounds binary search) ----------------
// wE per layer (1352 f32): [e1t 22x12][e2t 22x12][e3t 22x12][e4L 22x12][e4G 22x12][attv 32]
// Wt  per layer (32x352 bf16): Wt[o][d*11+kk] = conv_w[kk][d][o]  (o>=30 zero)
// owB per layer (2x64x8 bf16): owB[hf][lane][j] = outw[k*32 + hf*16 + n], k=(lane>>4)*8+j, n=lane&15
__global__ __launch_bounds__(256) void prep_kernel(const float* __restrict__ e1, const float* __restrict__ e2,
                                                   const float* __restrict__ e3, const float* __restrict__ e4,
                                                   const float* __restrict__ attv, const float* __restrict__ convw,
                                                   const float* __restrict__ outw,
                                                   const int* __restrict__ batch,
                                                   float* __restrict__ wE, bf16* __restrict__ Wt,
                                                   bf16* __restrict__ owB, int* __restrict__ gb) {
  int i = blockIdx.x * blockDim.x + threadIdx.x;
  if (i < 2 * 1352) {
    int l = i / 1352, r = i % 1352;
    float v = 0.f;
    if (r < 264)       { int q = r;        int j = q / 12, k = q % 12; if (k < 11) v = e1[l*242 + k*22 + j]; }
    else if (r < 528)  { int q = r - 264;  int j = q / 12, k = q % 12; if (k < 11) v = e2[l*242 + k*22 + j]; }
    else if (r < 792)  { int q = r - 528;  int j = q / 12, k = q % 12; if (k < 11) v = e3[l*242 + k*22 + j]; }
    else if (r < 1056) { int q = r - 792;  int j = q / 12, k = q % 12; if (k < 11) v = e4[l*484 + j*11 + k]; }
    else if (r < 1320) { int q = r - 1056; int j = q / 12, k = q % 12; if (k < 11) v = e4[l*484 + (22 + j)*11 + k]; }
    else               { int d = r - 1320; v = attv[l*32 + d]; }
    wE[i] = v;
  }
  int t = i - 2 * 1352;
  if (t >= 0 && t < 2 * 32 * 352) {
    int l = t / (32 * 352), q = t % (32 * 352);
    int o = q / 352, dk = q % 352;
    int d = dk / 11, kk = dk % 11;
    float v = 0.f;
    if (o < 30) v = convw[l*10560 + (kk*32 + d)*30 + o];
    Wt[t] = tob(v);
  }
  int u = i - 2 * 1352 - 2 * 32 * 352;
  if (u >= 0 && u < 2048) {
    int l = u >> 10, rem = u & 1023;
    int hf = rem >> 9, rem2 = rem & 511;
    int lane = rem2 >> 3, j = rem2 & 7;
    int k = (lane >> 4) * 8 + j, n = lane & 15;
    owB[u] = tob(outw[l*1024 + k*32 + hf*16 + n]);
  }
  int g = i - 2 * 1352 - 2 * 32 * 352 - 2048;
  if (g >= 0 && g <= N_GR) {
    if (g == N_GR) { gb[g] = N_NODES; }
    else {
      int lo = 0, hi = N_NODES;
      while (lo < hi) { int mid = (lo + hi) >> 1; if (batch[mid] < g) lo = mid + 1; else hi = mid; }
      gb[g] = lo;
    }
  }
}

// ---------------- fused embedding + h_proj(layer 0) ----------------
__global__ __launch_bounds__(256) void emb_hproj_kernel(const float* __restrict__ x, const float* __restrict__ w,
                                                        const float* __restrict__ b, const float* __restrict__ w1,
                                                        float* __restrict__ h, float* __restrict__ hp,
                                                        unsigned short* __restrict__ hpb, int N) {
  __shared__ float semb[16 * 32];
  __shared__ float sw1[32 * 32];
  __shared__ float sb[32];
  __shared__ float sx[8][16];
  __shared__ float sh[8][33];
  int tid = threadIdx.x;
  for (int i = tid; i < 16 * 32; i += 256) semb[i] = w[i];
  for (int i = tid; i < 32 * 32; i += 256) sw1[i] = w1[i];
  if (tid < 32) sb[tid] = b[tid];
  int nb = blockIdx.x * 8;
  if (tid < 128) {
    int n = nb + (tid >> 4), k = tid & 15;
    sx[tid >> 4][k] = (n < N) ? x[(size_t)n * 16 + k] : 0.f;
  }
  __syncthreads();
  int grp = tid >> 5, d = tid & 31;
  int n = nb + grp;
  float acc = sb[d];
  #pragma unroll
  for (int k = 0; k < 16; k++) acc += sx[grp][k] * semb[k*32 + d];
  sh[grp][d] = acc;
  if (n < N) h[(size_t)n * 32 + d] = acc;
  __syncthreads();
  float hpv = 0.f;
  #pragma unroll
  for (int k = 0; k < 32; k++) hpv += sh[grp][k] * sw1[k*32 + d];
  if (n < N) {
    hp[(size_t)n * 32 + d] = hpv;
    hpb[(size_t)n * 32 + d] = tobu(hpv);
  }
}

// ---------------- edge MLP + raw attention -> CSR-ordered payload ----------------
// payload[p] (32B, two uint4): {ea[0..7]}, {ea[8..10], raw(f32), src(int)}
__device__ __forceinline__ void loadw12(const float4* base, int idx3, float* w) {
  float4 a = base[idx3], b = base[idx3 + 1], c = base[idx3 + 2];
  w[0]=a.x; w[1]=a.y; w[2]=a.z; w[3]=a.w;
  w[4]=b.x; w[5]=b.y; w[6]=b.z; w[7]=b.w;
  w[8]=c.x; w[9]=c.y; w[10]=c.z; w[11]=c.w;
}

__global__ __launch_bounds__(256) void edge_kernel(const float* __restrict__ eattr,
                                                   const int* __restrict__ srcA,
                                                   const int* __restrict__ epos,
                                                   const unsigned short* __restrict__ hpb,
                                                   const float* __restrict__ wEl,
                                                   uint4* __restrict__ pay, int E) {
  const float4* w4 = (const float4*)wEl;
  int e = blockIdx.x * blockDim.x + threadIdx.x;
  bool live = e < E;
  float a[11], acc[11];
  #pragma unroll
  for (int k = 0; k < 11; k++) {
    a[k] = live ? eattr[(size_t)e*11 + k] : 0.f;
    acc[k] = 0.f;
  }
  for (int j = 0; j < 22; j++) {
    float w[12];
    loadw12(w4, j*3, w);
    float l1 = 0.f;
    #pragma unroll
    for (int k = 0; k < 11; k++) l1 += a[k] * w[k];
    loadw12(w4, 66 + j*3, w);
    float l2 = 0.f;
    #pragma unroll
    for (int k = 0; k < 11; k++) l2 += a[k] * w[k];
    loadw12(w4, 132 + j*3, w);
    float l3 = 0.f;
    #pragma unroll
    for (int k = 0; k < 11; k++) l3 += a[k] * w[k];
    float gg = tanh_fast(l2) * tanh_fast(l3);
    l1 = fmaxf(l1, 0.f);
    float wl[12], wg[12];
    loadw12(w4, 198 + j*3, wl);
    loadw12(w4, 264 + j*3, wg);
    #pragma unroll
    for (int k = 0; k < 11; k++) acc[k] += l1*wl[k] + gg*wg[k];
  }
  if (!live) return;
  const float* av = wEl + 1320;
  float mean = 0.f;
  #pragma unroll
  for (int k = 0; k < 11; k++) { acc[k] = fmaxf(acc[k], 0.f); mean += acc[k]; }
  mean *= (1.f / 11.f);
  int s = srcA[e];
  const uint2* hb = (const uint2*)(hpb + (size_t)s * 32);
  float dot = 0.f;
  #pragma unroll
  for (int q = 0; q < 8; q++) {
    uint2 hv = hb[q];
    dot += b2f((unsigned short)hv.x) * av[q*4+0] + b2f((unsigned short)(hv.x >> 16)) * av[q*4+1]
         + b2f((unsigned short)hv.y) * av[q*4+2] + b2f((unsigned short)(hv.y >> 16)) * av[q*4+3];
  }
  float raw = mean * dot;
  unsigned p[6];
  #pragma unroll
  for (int q = 0; q < 5; q++)
    p[q] = (unsigned)tobu(acc[2*q]) | ((unsigned)tobu(acc[2*q+1]) << 16);
  p[5] = (unsigned)tobu(acc[10]);
  int pp = epos[e];
  pay[(size_t)pp * 2]     = make_uint4(p[0], p[1], p[2], p[3]);
  pay[(size_t)pp * 2 + 1] = make_uint4(p[4], p[5], __float_as_uint(raw), (unsigned)s);
}

// ---------------- per-node aggregation: softmax scan then branch-free reduction ----------------
__device__ __forceinline__ void unpack_pay(uint4 p0, uint4 p1, float* ev) {
  ev[0] = b2f((unsigned short)p0.x); ev[1] = b2f((unsigned short)(p0.x >> 16));
  ev[2] = b2f((unsigned short)p0.y); ev[3] = b2f((unsigned short)(p0.y >> 16));
  ev[4] = b2f((unsigned short)p0.z); ev[5] = b2f((unsigned short)(p0.z >> 16));
  ev[6] = b2f((unsigned short)p0.w); ev[7] = b2f((unsigned short)(p0.w >> 16));
  ev[8] = b2f((unsigned short)p1.x); ev[9] = b2f((unsigned short)(p1.x >> 16));
  ev[10] = b2f((unsigned short)p1.y);
}

__global__ __launch_bounds__(256) void node_kernel(const int* __restrict__ offs, const int* __restrict__ elist,
                                                   const uint4* __restrict__ pay,
                                                   const unsigned short* __restrict__ hpb,
                                                   bf16* __restrict__ Abuf, float* __restrict__ atts, int N) {
  int wid = threadIdx.x >> 6, lane = threadIdx.x & 63;
  int half = lane >> 5, d = lane & 31;
  int n = blockIdx.x * 4 + wid;
  if (n >= N_PAD) return;
  int beg = 0, deg = 0;
  if (n < N) { beg = offs[n]; deg = offs[n + 1] - beg; }
  const float* payf = (const float*)pay;   // raw value of CSR slot p at payf[p*8+6]

  // --- phase 1: segment max, denom, atts (wave-parallel over edges) ---
  float m_l = -1e30f;
  for (int jj = lane; jj < deg; jj += 64)
    m_l = fmaxf(m_l, payf[(size_t)(beg + jj) * 8 + 6]);
  #pragma unroll
  for (int s = 1; s < 64; s <<= 1) m_l = fmaxf(m_l, __shfl_xor(m_l, s));
  float M = m_l;

  float s_l = 0.f;
  for (int jj = lane; jj < deg; jj += 64)
    s_l += __expf(payf[(size_t)(beg + jj) * 8 + 6] - M);
  #pragma unroll
  for (int s = 1; s < 64; s <<= 1) s_l += __shfl_xor(s_l, s);
  float inv = 1.f / (s_l + 1e-16f);

  for (int jj = lane; jj < deg; jj += 64) {
    float r = payf[(size_t)(beg + jj) * 8 + 6];
    atts[elist[beg + jj]] = __expf(r - M) * inv;
  }

  // --- phase 2: branch-free weighted reduction: agg[k] += ev[k] * (1+att)*xs ---
  float agg[11];
  #pragma unroll
  for (int k = 0; k < 11; k++) agg[k] = 0.f;

  int j = half;
  for (; j + 2 < deg; j += 4) {
    uint4 a0 = pay[(size_t)(beg + j) * 2],     a1 = pay[(size_t)(beg + j) * 2 + 1];
    uint4 b0 = pay[(size_t)(beg + j + 2) * 2], b1 = pay[(size_t)(beg + j + 2) * 2 + 1];
    float xa = b2f(hpb[(size_t)(int)a1.w * 32 + d]);
    float xb = b2f(hpb[(size_t)(int)b1.w * 32 + d]);
    float ca = 1.f + __expf(__uint_as_float(a1.z) - M) * inv;
    float cb = 1.f + __expf(__uint_as_float(b1.z) - M) * inv;
    float cxa = ca * xa, cxb = cb * xb;
    float eva[11], evb[11];
    unpack_pay(a0, a1, eva);
    unpack_pay(b0, b1, evb);
    #pragma unroll
    for (int k = 0; k < 11; k++) agg[k] += eva[k] * cxa + evb[k] * cxb;
  }
  for (; j < deg; j += 2) {
    uint4 q0 = pay[(size_t)(beg + j) * 2], q1 = pay[(size_t)(beg + j) * 2 + 1];
    float xs = b2f(hpb[(size_t)(int)q1.w * 32 + d]);
    float c = 1.f + __expf(__uint_as_float(q1.z) - M) * inv;
    float cx = c * xs;
    float ev[11];
    unpack_pay(q0, q1, ev);
    #pragma unroll
    for (int k = 0; k < 11; k++) agg[k] += ev[k] * cx;
  }

  #pragma unroll
  for (int k = 0; k < 11; k++) agg[k] += __shfl_xor(agg[k], 32);

  if (half == 0) {
    bf16* arow = Abuf + (size_t)n * 352 + d * 11;
    #pragma unroll
    for (int k = 0; k < 11; k++) arow[k] = tob(agg[k]);
  }
}

// ---------------- fused conv GEMM + epilogue (+ optional next-layer h_proj) ----------------
__global__ __launch_bounds__(256) void convfused_kernel(const short* __restrict__ A, const short* __restrict__ Wt,
                                                        const short* __restrict__ owB,
                                                        const float* __restrict__ hp, float* __restrict__ h,
                                                        const float* __restrict__ convb,
                                                        const float* __restrict__ s1w, const float* __restrict__ s1b,
                                                        const float* __restrict__ s2w, const float* __restrict__ s2b,
                                                        const float* __restrict__ outb,
                                                        const float* __restrict__ initw_next,
                                                        float* __restrict__ hp_out, unsigned short* __restrict__ hpb_out,
                                                        int N) {
  __shared__ short slo[64][40];
  __shared__ float sdelta[64][36];
  __shared__ float sskipw[128];
  __shared__ float sskipb[4];
  __shared__ float scb[32];
  __shared__ float sob[32];
  __shared__ float sw1[1024];
  int tid = threadIdx.x;
  if (tid < 64) sskipw[tid] = s1w[tid];
  if (tid >= 64 && tid < 128) sskipw[tid] = s2w[tid - 64];
  if (tid >= 128 && tid < 160) sob[tid - 128] = outb[tid - 128];
  if (tid >= 160 && tid < 192) scb[tid - 160] = (tid - 160 < 30) ? convb[tid - 160] : 0.f;
  if (tid >= 192 && tid < 196) sskipb[tid - 192] = (tid < 194) ? s1b[tid - 192] : s2b[tid - 194];
  if (initw_next) {
    for (int i = tid; i < 1024; i += 256) sw1[i] = initw_next[i];
  }
  __syncthreads();

  int wave = tid >> 6, lane = tid & 63;
  int r16 = lane & 15, kq = lane >> 4;
  int mbase = blockIdx.x * 64 + wave * 16;

  const short* arow = A + (size_t)(mbase + r16) * 352 + kq * 8;
  const short* b0p = Wt + (size_t)r16 * 352 + kq * 8;
  const short* b1p = b0p + 16 * 352;
  f32x4v acc0 = {0.f, 0.f, 0.f, 0.f}, acc1 = {0.f, 0.f, 0.f, 0.f};
  #pragma unroll
  for (int ks = 0; ks < 11; ks++) {
    bf16x8 af = *(const bf16x8*)(arow + ks * 32);
    bf16x8 b0 = *(const bf16x8*)(b0p + ks * 32);
    bf16x8 b1 = *(const bf16x8*)(b1p + ks * 32);
    acc0 = __builtin_amdgcn_mfma_f32_16x16x32_bf16(af, b0, acc0, 0, 0, 0);
    acc1 = __builtin_amdgcn_mfma_f32_16x16x32_bf16(af, b1, acc1, 0, 0, 0);
  }
  #pragma unroll
  for (int r = 0; r < 4; r++) {
    int row = wave * 16 + kq * 4 + r;
    slo[row][r16] = (short)tobu(fmaxf(acc0[r] + scb[r16], 0.f));
    if (r16 < 14) slo[row][16 + r16] = (short)tobu(fmaxf(acc1[r] + scb[16 + r16], 0.f));
  }
  __syncthreads();

  if (tid < 128) {
    int row = tid >> 1, jx = tid & 1;
    int grow = blockIdx.x * 64 + row;
    float a1 = sskipb[jx], a2 = sskipb[2 + jx];
    if (grow < N) {
      const float* hr = hp + (size_t)grow * 32;
      #pragma unroll
      for (int dd = 0; dd < 32; dd++) {
        float hv = hr[dd];
        a1 += hv * sskipw[dd*2 + jx];
        a2 += hv * sskipw[64 + dd*2 + jx];
      }
    }
    slo[row][30 + jx] = (short)tobu(tanh_fast(a1) * tanh_fast(a2));
  }
  __syncthreads();

  bf16x8 a2f = *(const bf16x8*)&slo[wave * 16 + r16][kq * 8];
  bf16x8 bo0 = *(const bf16x8*)(owB + lane * 8);
  bf16x8 bo1 = *(const bf16x8*)(owB + 512 + lane * 8);
  f32x4v d0 = {0.f, 0.f, 0.f, 0.f}, d1 = {0.f, 0.f, 0.f, 0.f};
  d0 = __builtin_amdgcn_mfma_f32_16x16x32_bf16(a2f, bo0, d0, 0, 0, 0);
  d1 = __builtin_amdgcn_mfma_f32_16x16x32_bf16(a2f, bo1, d1, 0, 0, 0);
  #pragma unroll
  for (int r = 0; r < 4; r++) {
    int row = wave * 16 + kq * 4 + r;
    sdelta[row][r16] = d0[r] + sob[r16];
    sdelta[row][16 + r16] = d1[r] + sob[16 + r16];
  }
  __syncthreads();

  int row = tid >> 2, col0 = (tid & 3) * 8;
  int grow = blockIdx.x * 64 + row;
  if (grow < N) {
    float* hr = h + (size_t)grow * 32 + col0;
    float4 ha = *(float4*)hr;
    float4 hb = *(float4*)(hr + 4);
    float4 da = *(float4*)&sdelta[row][col0];
    float4 db = *(float4*)&sdelta[row][col0 + 4];
    ha.x += da.x; ha.y += da.y; ha.z += da.z; ha.w += da.w;
    hb.x += db.x; hb.y += db.y; hb.z += db.z; hb.w += db.w;
    *(float4*)hr = ha;
    *(float4*)(hr + 4) = hb;
    *(float4*)&sdelta[row][col0] = ha;
    *(float4*)&sdelta[row][col0 + 4] = hb;
  }
  if (initw_next) {
    __syncthreads();
    if (grow < N) {
      float o[8];
      #pragma unroll
      for (int c = 0; c < 8; c++) o[c] = 0.f;
      #pragma unroll
      for (int k = 0; k < 32; k++) {
        float hv = sdelta[row][k];
        #pragma unroll
        for (int c = 0; c < 8; c++) o[c] += hv * sw1[k*32 + col0 + c];
      }
      float* hpo = hp_out + (size_t)grow * 32 + col0;
      unsigned short* hbo = hpb_out + (size_t)grow * 32 + col0;
      #pragma unroll
      for (int c = 0; c < 8; c++) { hpo[c] = o[c]; hbo[c] = tobu(o[c]); }
    }
  }
}

// ---------------- fused pool / outh / final head ----------------
__global__ __launch_bounds__(256) void pool2_kernel(const float* __restrict__ h, const int* __restrict__ gb,
                                                    const float* __restrict__ fw, const float* __restrict__ fb,
                                                    float* __restrict__ out0, float* __restrict__ outh) {
  __shared__ float part[8][32];
  __shared__ float pooled[32];
  int g = blockIdx.x;
  int s = gb[g], e = gb[g + 1];
  int grp = threadIdx.x >> 5, d = threadIdx.x & 31;
  float acc = 0.f;
  for (int n = s + grp; n < e; n += 8) {
    float v = h[(size_t)n * 32 + d];
    outh[(size_t)n * 32 + d] = v;
    acc += v;
  }
  part[grp][d] = acc;
  __syncthreads();
  if (threadIdx.x < 32) {
    float sum = 0.f;
    #pragma unroll
    for (int i = 0; i < 8; i++) sum += part[i][d];
    pooled[d] = sum / fmaxf((float)(e - s), 1.f);
  }
  __syncthreads();
  if (threadIdx.x < 32) {
    int jx = threadIdx.x;
    float o = fb[jx];
    #pragma unroll
    for (int dd = 0; dd < 32; dd++) o += pooled[dd] * fw[dd*32 + jx];
    out0[g * 32 + jx] = o;
  }
}

extern "C" void kernel_launch(void* const* d_in, const int* in_sizes, int n_in,
                              void* d_out, int out_size, void* d_ws, size_t ws_size,
                              hipStream_t stream) {
  (void)in_sizes; (void)n_in; (void)out_size; (void)ws_size;
  const float* x      = (const float*)d_in[0];
  const float* eattr  = (const float*)d_in[1];
  const int* eidx     = (const int*)d_in[2];
  const int* batch    = (const int*)d_in[3];
  const float* emb_w  = (const float*)d_in[4];
  const float* emb_b  = (const float*)d_in[5];
  const float* init_w = (const float*)d_in[6];
  const float* e1w    = (const float*)d_in[7];
  const float* e2w    = (const float*)d_in[8];
  const float* e3w    = (const float*)d_in[9];
  const float* e4w    = (const float*)d_in[10];
  const float* convw  = (const float*)d_in[11];
  const float* convb  = (const float*)d_in[12];
  const float* attv   = (const float*)d_in[13];
  const float* s1w    = (const float*)d_in[14];
  const float* s1b    = (const float*)d_in[15];
  const float* s2w    = (const float*)d_in[16];
  const float* s2b    = (const float*)d_in[17];
  const float* outw   = (const float*)d_in[18];
  const float* outb   = (const float*)d_in[19];
  const float* finw   = (const float*)d_in[20];
  const float* finb   = (const float*)d_in[21];

  char* ws = (char*)d_ws;
  size_t off = 0;
  auto take = [&](size_t bytes) -> char* {
    char* p = ws + off;
    off += (bytes + 255) & ~(size_t)255;
    return p;
  };
  float* h    = (float*)take((size_t)N_NODES * 32 * 4);
  float* hp   = (float*)take((size_t)N_NODES * 32 * 4);
  unsigned short* hpb = (unsigned short*)take((size_t)N_NODES * 32 * 2);
  uint4* pay  = (uint4*)take((size_t)N_EDGES * 32);
  bf16*  Abuf = (bf16*)take((size_t)N_PAD * 352 * 2);
  int*   deg  = (int*)take((size_t)N_NODES * 4);
  int*   offs = (int*)take((size_t)(N_NODES + 1) * 4);
  int*   cur  = (int*)take((size_t)N_NODES * 4);
  int*   elist= (int*)take((size_t)N_EDGES * 4);
  int*   epos = (int*)take((size_t)N_EDGES * 4);
  int*   gb   = (int*)take((size_t)(N_GR + 1) * 4);
  float* wE   = (float*)take((size_t)2 * 1352 * 4);
  bf16*  Wt   = (bf16*)take((size_t)2 * 32 * 352 * 2);
  bf16*  owB  = (bf16*)take((size_t)2048 * 2);

  float* out0 = (float*)d_out;
  float* outh = out0 + N_GR * 32;
  float* outa = outh + (size_t)N_NODES * 32;

  const int* srcA = eidx;
  const int* dstA = eidx + N_EDGES;

  hipMemsetAsync(deg, 0, (size_t)N_NODES * 4, stream);

  prep_kernel<<<107, 256, 0, stream>>>(e1w, e2w, e3w, e4w, attv, convw, outw, batch, wE, Wt, owB, gb);
  hist_kernel<<<(N_EDGES + 255) / 256, 256, 0, stream>>>(dstA, deg, N_EDGES);
  scan_kernel<<<1, 1024, 0, stream>>>(deg, offs, cur, N_NODES);
  fill_kernel<<<(N_EDGES + 255) / 256, 256, 0, stream>>>(dstA, cur, elist, epos, N_EDGES);
  emb_hproj_kernel<<<(N_NODES + 7) / 8, 256, 0, stream>>>(x, emb_w, emb_b, init_w, h, hp, hpb, N_NODES);

  for (int l = 0; l < 2; l++) {
    edge_kernel<<<(N_EDGES + 255) / 256, 256, 0, stream>>>(
        eattr, srcA, epos, hpb, wE + l * 1352, pay, N_EDGES);
    node_kernel<<<N_PAD / 4, 256, 0, stream>>>(offs, elist, pay, hpb,
                                               Abuf, outa + (size_t)l * N_EDGES, N_NODES);
    convfused_kernel<<<N_PAD / 64, 256, 0, stream>>>(
        (const short*)Abuf, (const short*)Wt + (size_t)l * 32 * 352, (const short*)owB + (size_t)l * 1024,
        hp, h, convb + l * 30, s1w + l * 64, s1b + l * 2, s2w + l * 64, s2b + l * 2,
        outb + l * 32,
        (l == 0) ? (init_w + 1024) : nullptr, hp, hpb, N_NODES);
  }

  pool2_kernel<<<N_GR, 256, 0, stream>>>(h, gb, finw, finb, out0, outh);
}

// Round 7
// 230.960 us; speedup vs baseline: 1.9162x; 1.0674x over previous
//
#include <hip/hip_runtime.h>
#include <hip/hip_bf16.h>

typedef __hip_bfloat16 bf16;
using f32x4v = __attribute__((ext_vector_type(4))) float;
using bf16x8 = __attribute__((ext_vector_type(8))) short;

#define N_NODES 25000
#define N_PAD   25024   // multiple of 32 for conv kernel tiles
#define N_EDGES 400000
#define N_GR    100
#define SCAN_C  25      // 1024 * 25 = 25600 >= N_NODES

__device__ __forceinline__ bf16 tob(float v) { return __float2bfloat16(v); }
__device__ __forceinline__ unsigned short tobu(float v) {
  union { bf16 b; unsigned short u; } c; c.b = __float2bfloat16(v); return c.u;
}
__device__ __forceinline__ float b2f(unsigned short u) { return __uint_as_float(((unsigned)u) << 16); }
// clamp-free tanh: 1 - 2/(e^{2x}+1); inf-safe
__device__ __forceinline__ float tanh_fast(float x) {
  float e = __expf(2.f * x);
  return 1.f - 2.f * __builtin_amdgcn_rcpf(e + 1.f);
}

// ---------------- CSR build ----------------
__global__ __launch_bounds__(256) void hist_kernel(const int* __restrict__ dst, int* __restrict__ deg, int E) {
  int e = blockIdx.x * blockDim.x + threadIdx.x;
  if (e < E) atomicAdd(&deg[dst[e]], 1);
}

// one-pass scan: thread-local 25-chunk scan in registers + block scan of totals
__global__ __launch_bounds__(1024) void scan_kernel(const int* __restrict__ deg, int* __restrict__ offs,
                                                    int* __restrict__ cur, int n) {
  __shared__ int wsum[16];
  __shared__ int wpre[16];
  int t = threadIdx.x, lane = t & 63, w = t >> 6;
  int base = t * SCAN_C;
  int loc[SCAN_C];
  int s = 0;
  #pragma unroll
  for (int i = 0; i < SCAN_C; i++) {
    int idx = base + i;
    int v = (idx < n) ? deg[idx] : 0;
    loc[i] = s; s += v;
  }
  int x = s;
  #pragma unroll
  for (int sh = 1; sh < 64; sh <<= 1) { int y = __shfl_up(x, sh); if (lane >= sh) x += y; }
  if (lane == 63) wsum[w] = x;
  __syncthreads();
  if (w == 0 && lane < 16) {
    int ws_ = wsum[lane], xs = ws_;
    #pragma unroll
    for (int sh = 1; sh < 16; sh <<= 1) { int y = __shfl_up(xs, sh); if (lane >= sh) xs += y; }
    wpre[lane] = xs - ws_;
  }
  __syncthreads();
  int excl = wpre[w] + x - s;
  #pragma unroll
  for (int i = 0; i < SCAN_C; i++) {
    int idx = base + i;
    if (idx < n) { int o = excl + loc[i]; offs[idx] = o; cur[idx] = o; }
  }
  if (t == 1023) offs[n] = excl + s;
}

// ---------------- weight prep (+ zero deg + graph bounds) ----------------
__global__ __launch_bounds__(256) void prep_kernel(const float* __restrict__ e1, const float* __restrict__ e2,
                                                   const float* __restrict__ e3, const float* __restrict__ e4,
                                                   const float* __restrict__ attv, const float* __restrict__ convw,
                                                   const float* __restrict__ outw,
                                                   const int* __restrict__ batch,
                                                   float* __restrict__ wE, bf16* __restrict__ Wt,
                                                   bf16* __restrict__ owB, int* __restrict__ gb,
                                                   int* __restrict__ deg) {
  int i = blockIdx.x * blockDim.x + threadIdx.x;
  if (i < N_NODES) deg[i] = 0;
  if (i < 2 * 1352) {
    int l = i / 1352, r = i % 1352;
    float v = 0.f;
    if (r < 264)       { int q = r;        int j = q / 12, k = q % 12; if (k < 11) v = e1[l*242 + k*22 + j]; }
    else if (r < 528)  { int q = r - 264;  int j = q / 12, k = q % 12; if (k < 11) v = e2[l*242 + k*22 + j]; }
    else if (r < 792)  { int q = r - 528;  int j = q / 12, k = q % 12; if (k < 11) v = e3[l*242 + k*22 + j]; }
    else if (r < 1056) { int q = r - 792;  int j = q / 12, k = q % 12; if (k < 11) v = e4[l*484 + j*11 + k]; }
    else if (r < 1320) { int q = r - 1056; int j = q / 12, k = q % 12; if (k < 11) v = e4[l*484 + (22 + j)*11 + k]; }
    else               { int d = r - 1320; v = attv[l*32 + d]; }
    wE[i] = v;
  }
  int t = i - 2 * 1352;
  if (t >= 0 && t < 2 * 32 * 352) {
    int l = t / (32 * 352), q = t % (32 * 352);
    int o = q / 352, dk = q % 352;
    int d = dk / 11, kk = dk % 11;
    float v = 0.f;
    if (o < 30) v = convw[l*10560 + (kk*32 + d)*30 + o];
    Wt[t] = tob(v);
  }
  int u = i - 2 * 1352 - 2 * 32 * 352;
  if (u >= 0 && u < 2048) {
    int l = u >> 10, rem = u & 1023;
    int hf = rem >> 9, rem2 = rem & 511;
    int lane = rem2 >> 3, j = rem2 & 7;
    int k = (lane >> 4) * 8 + j, n = lane & 15;
    owB[u] = tob(outw[l*1024 + k*32 + hf*16 + n]);
  }
  int g = i - 2 * 1352 - 2 * 32 * 352 - 2048;
  if (g >= 0 && g <= N_GR) {
    if (g == N_GR) { gb[g] = N_NODES; }
    else {
      int lo = 0, hi = N_NODES;
      while (lo < hi) { int mid = (lo + hi) >> 1; if (batch[mid] < g) lo = mid + 1; else hi = mid; }
      gb[g] = lo;
    }
  }
}

// ---------------- fused embedding + h_proj(layer 0) ----------------
__global__ __launch_bounds__(256) void emb_hproj_kernel(const float* __restrict__ x, const float* __restrict__ w,
                                                        const float* __restrict__ b, const float* __restrict__ w1,
                                                        float* __restrict__ h, float* __restrict__ hp,
                                                        unsigned short* __restrict__ hpb, int N) {
  __shared__ float semb[16 * 32];
  __shared__ float sw1[32 * 32];
  __shared__ float sb[32];
  __shared__ float sx[8][16];
  __shared__ float sh[8][33];
  int tid = threadIdx.x;
  for (int i = tid; i < 16 * 32; i += 256) semb[i] = w[i];
  for (int i = tid; i < 32 * 32; i += 256) sw1[i] = w1[i];
  if (tid < 32) sb[tid] = b[tid];
  int nb = blockIdx.x * 8;
  if (tid < 128) {
    int n = nb + (tid >> 4), k = tid & 15;
    sx[tid >> 4][k] = (n < N) ? x[(size_t)n * 16 + k] : 0.f;
  }
  __syncthreads();
  int grp = tid >> 5, d = tid & 31;
  int n = nb + grp;
  float acc = sb[d];
  #pragma unroll
  for (int k = 0; k < 16; k++) acc += sx[grp][k] * semb[k*32 + d];
  sh[grp][d] = acc;
  if (n < N) h[(size_t)n * 32 + d] = acc;
  __syncthreads();
  float hpv = 0.f;
  #pragma unroll
  for (int k = 0; k < 32; k++) hpv += sh[grp][k] * sw1[k*32 + d];
  if (n < N) {
    hp[(size_t)n * 32 + d] = hpv;
    hpb[(size_t)n * 32 + d] = tobu(hpv);
  }
}

// ---------------- edge MLP + raw attention -> CSR payload (+ inline fill on first layer) ----------------
__device__ __forceinline__ void loadw12(const float4* base, int idx3, float* w) {
  float4 a = base[idx3], b = base[idx3 + 1], c = base[idx3 + 2];
  w[0]=a.x; w[1]=a.y; w[2]=a.z; w[3]=a.w;
  w[4]=b.x; w[5]=b.y; w[6]=b.z; w[7]=b.w;
  w[8]=c.x; w[9]=c.y; w[10]=c.z; w[11]=c.w;
}

__global__ __launch_bounds__(256) void edge_kernel(const float* __restrict__ eattr,
                                                   const int* __restrict__ srcA,
                                                   const int* __restrict__ dstA,
                                                   int* __restrict__ cur,
                                                   int* __restrict__ elist,
                                                   int* __restrict__ epos,
                                                   const unsigned short* __restrict__ hpb,
                                                   const float* __restrict__ wEl,
                                                   uint4* __restrict__ pay, int first, int E) {
  const float4* w4 = (const float4*)wEl;
  int e = blockIdx.x * blockDim.x + threadIdx.x;
  bool live = e < E;
  float a[11], acc[11];
  #pragma unroll
  for (int k = 0; k < 11; k++) {
    a[k] = live ? eattr[(size_t)e*11 + k] : 0.f;
    acc[k] = 0.f;
  }
  // CSR slot assignment overlapped with the MLP compute
  int pp = 0;
  if (live) {
    if (first) {
      pp = atomicAdd(&cur[dstA[e]], 1);
      elist[pp] = e;
      epos[e] = pp;
    } else {
      pp = epos[e];
    }
  }
  for (int j = 0; j < 22; j++) {
    float w[12];
    loadw12(w4, j*3, w);
    float l1 = 0.f;
    #pragma unroll
    for (int k = 0; k < 11; k++) l1 += a[k] * w[k];
    loadw12(w4, 66 + j*3, w);
    float l2 = 0.f;
    #pragma unroll
    for (int k = 0; k < 11; k++) l2 += a[k] * w[k];
    loadw12(w4, 132 + j*3, w);
    float l3 = 0.f;
    #pragma unroll
    for (int k = 0; k < 11; k++) l3 += a[k] * w[k];
    float gg = tanh_fast(l2) * tanh_fast(l3);
    l1 = fmaxf(l1, 0.f);
    float wl[12], wg[12];
    loadw12(w4, 198 + j*3, wl);
    loadw12(w4, 264 + j*3, wg);
    #pragma unroll
    for (int k = 0; k < 11; k++) acc[k] += l1*wl[k] + gg*wg[k];
  }
  if (!live) return;
  const float* av = wEl + 1320;
  float mean = 0.f;
  #pragma unroll
  for (int k = 0; k < 11; k++) { acc[k] = fmaxf(acc[k], 0.f); mean += acc[k]; }
  mean *= (1.f / 11.f);
  int s = srcA[e];
  const uint2* hb = (const uint2*)(hpb + (size_t)s * 32);
  float dot = 0.f;
  #pragma unroll
  for (int q = 0; q < 8; q++) {
    uint2 hv = hb[q];
    dot += b2f((unsigned short)hv.x) * av[q*4+0] + b2f((unsigned short)(hv.x >> 16)) * av[q*4+1]
         + b2f((unsigned short)hv.y) * av[q*4+2] + b2f((unsigned short)(hv.y >> 16)) * av[q*4+3];
  }
  float raw = mean * dot;
  unsigned p[6];
  #pragma unroll
  for (int q = 0; q < 5; q++)
    p[q] = (unsigned)tobu(acc[2*q]) | ((unsigned)tobu(acc[2*q+1]) << 16);
  p[5] = (unsigned)tobu(acc[10]);
  pay[(size_t)pp * 2]     = make_uint4(p[0], p[1], p[2], p[3]);
  pay[(size_t)pp * 2 + 1] = make_uint4(p[4], p[5], __float_as_uint(raw), (unsigned)s);
}

// ---------------- per-node aggregation: softmax scan then branch-free reduction ----------------
__device__ __forceinline__ void unpack_pay(uint4 p0, uint4 p1, float* ev) {
  ev[0] = b2f((unsigned short)p0.x); ev[1] = b2f((unsigned short)(p0.x >> 16));
  ev[2] = b2f((unsigned short)p0.y); ev[3] = b2f((unsigned short)(p0.y >> 16));
  ev[4] = b2f((unsigned short)p0.z); ev[5] = b2f((unsigned short)(p0.z >> 16));
  ev[6] = b2f((unsigned short)p0.w); ev[7] = b2f((unsigned short)(p0.w >> 16));
  ev[8] = b2f((unsigned short)p1.x); ev[9] = b2f((unsigned short)(p1.x >> 16));
  ev[10] = b2f((unsigned short)p1.y);
}

__global__ __launch_bounds__(256) void node_kernel(const int* __restrict__ offs, const int* __restrict__ elist,
                                                   const uint4* __restrict__ pay,
                                                   const unsigned short* __restrict__ hpb,
                                                   bf16* __restrict__ Abuf, float* __restrict__ atts, int N) {
  int wid = threadIdx.x >> 6, lane = threadIdx.x & 63;
  int half = lane >> 5, d = lane & 31;
  int n = blockIdx.x * 4 + wid;
  if (n >= N_PAD) return;
  int beg = 0, deg = 0;
  if (n < N) { beg = offs[n]; deg = offs[n + 1] - beg; }
  const float* payf = (const float*)pay;

  float M, inv;
  float einv_reg = 0.f;
  bool fast = (deg <= 64);
  if (fast) {
    // phase 1 entirely in registers: one scattered load per lane
    float r = (lane < deg) ? payf[(size_t)(beg + lane) * 8 + 6] : -1e30f;
    float mm = r;
    #pragma unroll
    for (int sh = 1; sh < 64; sh <<= 1) mm = fmaxf(mm, __shfl_xor(mm, sh));
    M = mm;
    float ex = (lane < deg) ? __expf(r - M) : 0.f;
    float ss = ex;
    #pragma unroll
    for (int sh = 1; sh < 64; sh <<= 1) ss += __shfl_xor(ss, sh);
    inv = 1.f / (ss + 1e-16f);
    einv_reg = ex * inv;
    if (lane < deg) atts[elist[beg + lane]] = einv_reg;
  } else {
    float m_l = -1e30f;
    for (int jj = lane; jj < deg; jj += 64)
      m_l = fmaxf(m_l, payf[(size_t)(beg + jj) * 8 + 6]);
    #pragma unroll
    for (int sh = 1; sh < 64; sh <<= 1) m_l = fmaxf(m_l, __shfl_xor(m_l, sh));
    M = m_l;
    float s_l = 0.f;
    for (int jj = lane; jj < deg; jj += 64)
      s_l += __expf(payf[(size_t)(beg + jj) * 8 + 6] - M);
    #pragma unroll
    for (int sh = 1; sh < 64; sh <<= 1) s_l += __shfl_xor(s_l, sh);
    inv = 1.f / (s_l + 1e-16f);
    for (int jj = lane; jj < deg; jj += 64) {
      float r = payf[(size_t)(beg + jj) * 8 + 6];
      atts[elist[beg + jj]] = __expf(r - M) * inv;
    }
  }

  // phase 2: branch-free weighted reduction: agg[k] += ev[k] * (1+att)*xs
  float agg[11];
  #pragma unroll
  for (int k = 0; k < 11; k++) agg[k] = 0.f;

  int j = half;
  for (; j + 2 < deg; j += 4) {
    uint4 a0 = pay[(size_t)(beg + j) * 2],     a1 = pay[(size_t)(beg + j) * 2 + 1];
    uint4 b0 = pay[(size_t)(beg + j + 2) * 2], b1 = pay[(size_t)(beg + j + 2) * 2 + 1];
    float xa = b2f(hpb[(size_t)(int)a1.w * 32 + d]);
    float xb = b2f(hpb[(size_t)(int)b1.w * 32 + d]);
    float ca = fast ? (1.f + __shfl(einv_reg, j))
                    : (1.f + __expf(__uint_as_float(a1.z) - M) * inv);
    float cb = fast ? (1.f + __shfl(einv_reg, j + 2))
                    : (1.f + __expf(__uint_as_float(b1.z) - M) * inv);
    float cxa = ca * xa, cxb = cb * xb;
    float eva[11], evb[11];
    unpack_pay(a0, a1, eva);
    unpack_pay(b0, b1, evb);
    #pragma unroll
    for (int k = 0; k < 11; k++) agg[k] += eva[k] * cxa + evb[k] * cxb;
  }
  for (; j < deg; j += 2) {
    uint4 q0 = pay[(size_t)(beg + j) * 2], q1 = pay[(size_t)(beg + j) * 2 + 1];
    float xs = b2f(hpb[(size_t)(int)q1.w * 32 + d]);
    float c = fast ? (1.f + __shfl(einv_reg, j))
                   : (1.f + __expf(__uint_as_float(q1.z) - M) * inv);
    float cx = c * xs;
    float ev[11];
    unpack_pay(q0, q1, ev);
    #pragma unroll
    for (int k = 0; k < 11; k++) agg[k] += ev[k] * cx;
  }

  #pragma unroll
  for (int k = 0; k < 11; k++) agg[k] += __shfl_xor(agg[k], 32);

  if (half == 0) {
    bf16* arow = Abuf + (size_t)n * 352 + d * 11;
    #pragma unroll
    for (int k = 0; k < 11; k++) arow[k] = tob(agg[k]);
  }
}

// ---------------- fused conv GEMM + epilogue (+ optional next-layer h_proj) ----------------
// 32 rows per block, 128 threads (2 waves) for occupancy
__global__ __launch_bounds__(128) void convfused_kernel(const short* __restrict__ A, const short* __restrict__ Wt,
                                                        const short* __restrict__ owB,
                                                        const float* __restrict__ hp, float* __restrict__ h,
                                                        const float* __restrict__ convb,
                                                        const float* __restrict__ s1w, const float* __restrict__ s1b,
                                                        const float* __restrict__ s2w, const float* __restrict__ s2b,
                                                        const float* __restrict__ outb,
                                                        const float* __restrict__ initw_next,
                                                        float* __restrict__ hp_out, unsigned short* __restrict__ hpb_out,
                                                        int N) {
  __shared__ short slo[32][40];
  __shared__ float sdelta[32][36];
  __shared__ float sskipw[128];
  __shared__ float sskipb[4];
  __shared__ float scb[32];
  __shared__ float sob[32];
  __shared__ float sw1[1024];
  int tid = threadIdx.x;
  if (tid < 64) sskipw[tid] = s1w[tid];
  if (tid >= 64 && tid < 128) sskipw[tid] = s2w[tid - 64];
  if (tid < 32) sob[tid] = outb[tid];
  if (tid >= 32 && tid < 64) scb[tid - 32] = (tid - 32 < 30) ? convb[tid - 32] : 0.f;
  if (tid >= 96 && tid < 100) sskipb[tid - 96] = (tid < 98) ? s1b[tid - 96] : s2b[tid - 98];
  if (initw_next) {
    for (int i = tid; i < 1024; i += 128) sw1[i] = initw_next[i];
  }
  __syncthreads();

  int wave = tid >> 6, lane = tid & 63;
  int r16 = lane & 15, kq = lane >> 4;
  int mbase = blockIdx.x * 32 + wave * 16;

  const short* arow = A + (size_t)(mbase + r16) * 352 + kq * 8;
  const short* b0p = Wt + (size_t)r16 * 352 + kq * 8;
  const short* b1p = b0p + 16 * 352;
  f32x4v acc0 = {0.f, 0.f, 0.f, 0.f}, acc1 = {0.f, 0.f, 0.f, 0.f};
  #pragma unroll
  for (int ks = 0; ks < 11; ks++) {
    bf16x8 af = *(const bf16x8*)(arow + ks * 32);
    bf16x8 b0 = *(const bf16x8*)(b0p + ks * 32);
    bf16x8 b1 = *(const bf16x8*)(b1p + ks * 32);
    acc0 = __builtin_amdgcn_mfma_f32_16x16x32_bf16(af, b0, acc0, 0, 0, 0);
    acc1 = __builtin_amdgcn_mfma_f32_16x16x32_bf16(af, b1, acc1, 0, 0, 0);
  }
  #pragma unroll
  for (int r = 0; r < 4; r++) {
    int row = wave * 16 + kq * 4 + r;
    slo[row][r16] = (short)tobu(fmaxf(acc0[r] + scb[r16], 0.f));
    if (r16 < 14) slo[row][16 + r16] = (short)tobu(fmaxf(acc1[r] + scb[16 + r16], 0.f));
  }
  __syncthreads();

  if (tid < 64) {
    int row = tid >> 1, jx = tid & 1;
    int grow = blockIdx.x * 32 + row;
    float a1 = sskipb[jx], a2 = sskipb[2 + jx];
    if (grow < N) {
      const float* hr = hp + (size_t)grow * 32;
      #pragma unroll
      for (int dd = 0; dd < 32; dd++) {
        float hv = hr[dd];
        a1 += hv * sskipw[dd*2 + jx];
        a2 += hv * sskipw[64 + dd*2 + jx];
      }
    }
    slo[row][30 + jx] = (short)tobu(tanh_fast(a1) * tanh_fast(a2));
  }
  __syncthreads();

  bf16x8 a2f = *(const bf16x8*)&slo[wave * 16 + r16][kq * 8];
  bf16x8 bo0 = *(const bf16x8*)(owB + lane * 8);
  bf16x8 bo1 = *(const bf16x8*)(owB + 512 + lane * 8);
  f32x4v d0 = {0.f, 0.f, 0.f, 0.f}, d1 = {0.f, 0.f, 0.f, 0.f};
  d0 = __builtin_amdgcn_mfma_f32_16x16x32_bf16(a2f, bo0, d0, 0, 0, 0);
  d1 = __builtin_amdgcn_mfma_f32_16x16x32_bf16(a2f, bo1, d1, 0, 0, 0);
  #pragma unroll
  for (int r = 0; r < 4; r++) {
    int row = wave * 16 + kq * 4 + r;
    sdelta[row][r16] = d0[r] + sob[r16];
    sdelta[row][16 + r16] = d1[r] + sob[16 + r16];
  }
  __syncthreads();

  int row = tid >> 2, col0 = (tid & 3) * 8;
  int grow = blockIdx.x * 32 + row;
  if (grow < N) {
    float* hr = h + (size_t)grow * 32 + col0;
    float4 ha = *(float4*)hr;
    float4 hb = *(float4*)(hr + 4);
    float4 da = *(float4*)&sdelta[row][col0];
    float4 db = *(float4*)&sdelta[row][col0 + 4];
    ha.x += da.x; ha.y += da.y; ha.z += da.z; ha.w += da.w;
    hb.x += db.x; hb.y += db.y; hb.z += db.z; hb.w += db.w;
    *(float4*)hr = ha;
    *(float4*)(hr + 4) = hb;
    *(float4*)&sdelta[row][col0] = ha;
    *(float4*)&sdelta[row][col0 + 4] = hb;
  }
  if (initw_next) {
    __syncthreads();
    if (grow < N) {
      float o[8];
      #pragma unroll
      for (int c = 0; c < 8; c++) o[c] = 0.f;
      #pragma unroll
      for (int k = 0; k < 32; k++) {
        float hv = sdelta[row][k];
        #pragma unroll
        for (int c = 0; c < 8; c++) o[c] += hv * sw1[k*32 + col0 + c];
      }
      float* hpo = hp_out + (size_t)grow * 32 + col0;
      unsigned short* hbo = hpb_out + (size_t)grow * 32 + col0;
      #pragma unroll
      for (int c = 0; c < 8; c++) { hpo[c] = o[c]; hbo[c] = tobu(o[c]); }
    }
  }
}

// ---------------- fused pool / outh / final head ----------------
__global__ __launch_bounds__(256) void pool2_kernel(const float* __restrict__ h, const int* __restrict__ gb,
                                                    const float* __restrict__ fw, const float* __restrict__ fb,
                                                    float* __restrict__ out0, float* __restrict__ outh) {
  __shared__ float part[8][32];
  __shared__ float pooled[32];
  int g = blockIdx.x;
  int s = gb[g], e = gb[g + 1];
  int grp = threadIdx.x >> 5, d = threadIdx.x & 31;
  float acc = 0.f;
  for (int n = s + grp; n < e; n += 8) {
    float v = h[(size_t)n * 32 + d];
    outh[(size_t)n * 32 + d] = v;
    acc += v;
  }
  part[grp][d] = acc;
  __syncthreads();
  if (threadIdx.x < 32) {
    float sum = 0.f;
    #pragma unroll
    for (int i = 0; i < 8; i++) sum += part[i][d];
    pooled[d] = sum / fmaxf((float)(e - s), 1.f);
  }
  __syncthreads();
  if (threadIdx.x < 32) {
    int jx = threadIdx.x;
    float o = fb[jx];
    #pragma unroll
    for (int dd = 0; dd < 32; dd++) o += pooled[dd] * fw[dd*32 + jx];
    out0[g * 32 + jx] = o;
  }
}

extern "C" void kernel_launch(void* const* d_in, const int* in_sizes, int n_in,
                              void* d_out, int out_size, void* d_ws, size_t ws_size,
                              hipStream_t stream) {
  (void)in_sizes; (void)n_in; (void)out_size; (void)ws_size;
  const float* x      = (const float*)d_in[0];
  const float* eattr  = (const float*)d_in[1];
  const int* eidx     = (const int*)d_in[2];
  const int* batch    = (const int*)d_in[3];
  const float* emb_w  = (const float*)d_in[4];
  const float* emb_b  = (const float*)d_in[5];
  const float* init_w = (const float*)d_in[6];
  const float* e1w    = (const float*)d_in[7];
  const float* e2w    = (const float*)d_in[8];
  const float* e3w    = (const float*)d_in[9];
  const float* e4w    = (const float*)d_in[10];
  const float* convw  = (const float*)d_in[11];
  const float* convb  = (const float*)d_in[12];
  const float* attv   = (const float*)d_in[13];
  const float* s1w    = (const float*)d_in[14];
  const float* s1b    = (const float*)d_in[15];
  const float* s2w    = (const float*)d_in[16];
  const float* s2b    = (const float*)d_in[17];
  const float* outw   = (const float*)d_in[18];
  const float* outb   = (const float*)d_in[19];
  const float* finw   = (const float*)d_in[20];
  const float* finb   = (const float*)d_in[21];

  char* ws = (char*)d_ws;
  size_t off = 0;
  auto take = [&](size_t bytes) -> char* {
    char* p = ws + off;
    off += (bytes + 255) & ~(size_t)255;
    return p;
  };
  float* h    = (float*)take((size_t)N_NODES * 32 * 4);
  float* hp   = (float*)take((size_t)N_NODES * 32 * 4);
  unsigned short* hpb = (unsigned short*)take((size_t)N_NODES * 32 * 2);
  uint4* pay  = (uint4*)take((size_t)N_EDGES * 32);
  bf16*  Abuf = (bf16*)take((size_t)N_PAD * 352 * 2);
  int*   deg  = (int*)take((size_t)N_NODES * 4);
  int*   offs = (int*)take((size_t)(N_NODES + 1) * 4);
  int*   cur  = (int*)take((size_t)N_NODES * 4);
  int*   elist= (int*)take((size_t)N_EDGES * 4);
  int*   epos = (int*)take((size_t)N_EDGES * 4);
  int*   gb   = (int*)take((size_t)(N_GR + 1) * 4);
  float* wE   = (float*)take((size_t)2 * 1352 * 4);
  bf16*  Wt   = (bf16*)take((size_t)2 * 32 * 352 * 2);
  bf16*  owB  = (bf16*)take((size_t)2048 * 2);

  float* out0 = (float*)d_out;
  float* outh = out0 + N_GR * 32;
  float* outa = outh + (size_t)N_NODES * 32;

  const int* srcA = eidx;
  const int* dstA = eidx + N_EDGES;

  prep_kernel<<<107, 256, 0, stream>>>(e1w, e2w, e3w, e4w, attv, convw, outw, batch, wE, Wt, owB, gb, deg);
  hist_kernel<<<(N_EDGES + 255) / 256, 256, 0, stream>>>(dstA, deg, N_EDGES);
  scan_kernel<<<1, 1024, 0, stream>>>(deg, offs, cur, N_NODES);
  emb_hproj_kernel<<<(N_NODES + 7) / 8, 256, 0, stream>>>(x, emb_w, emb_b, init_w, h, hp, hpb, N_NODES);

  for (int l = 0; l < 2; l++) {
    edge_kernel<<<(N_EDGES + 255) / 256, 256, 0, stream>>>(
        eattr, srcA, dstA, cur, elist, epos, hpb, wE + l * 1352, pay, (l == 0) ? 1 : 0, N_EDGES);
    node_kernel<<<N_PAD / 4, 256, 0, stream>>>(offs, elist, pay, hpb,
                                               Abuf, outa + (size_t)l * N_EDGES, N_NODES);
    convfused_kernel<<<N_PAD / 32, 128, 0, stream>>>(
        (const short*)Abuf, (const short*)Wt + (size_t)l * 32 * 352, (const short*)owB + (size_t)l * 1024,
        hp, h, convb + l * 30, s1w + l * 64, s1b + l * 2, s2w + l * 64, s2b + l * 2,
        outb + l * 32,
        (l == 0) ? (init_w + 1024) : nullptr, hp, hpb, N_NODES);
  }

  pool2_kernel<<<N_GR, 256, 0, stream>>>(h, gb, finw, finb, out0, outh);
}